// Round 12
// baseline (400.190 us; speedup 1.0000x reference)
//
#include <hip/hip_runtime.h>
#include <math.h>

typedef unsigned short u16;
typedef __bf16 bf16x8 __attribute__((ext_vector_type(8)));
typedef float f32x4 __attribute__((ext_vector_type(4)));

#define SEQ 2048
#define ATT_SCALE 0.08838834764831845f

__device__ __forceinline__ u16 f2bf(float f){
  union{float f;unsigned u;}v; v.f=f;
  unsigned r=v.u + 0x7fffu + ((v.u>>16)&1u);
  return (u16)(r>>16);
}
__device__ __forceinline__ float bf2f(u16 u){
  union{unsigned u;float f;}v; v.u=((unsigned)u)<<16; return v.f;
}
__device__ __forceinline__ f32x4 f4zero(){ f32x4 v; v[0]=0.f;v[1]=0.f;v[2]=0.f;v[3]=0.f; return v; }
__device__ __forceinline__ f32x4 mfma16(bf16x8 a, bf16x8 b, f32x4 c){
  return __builtin_amdgcn_mfma_f32_16x16x32_bf16(a,b,c,0,0,0);
}

typedef const __attribute__((address_space(1))) unsigned char* gas1p;
typedef __attribute__((address_space(3))) unsigned char* las3p;
__device__ __forceinline__ void gld16(const void* g, void* l){
  __builtin_amdgcn_global_load_lds((gas1p)g, (las3p)l, 16, 0, 0);
}

// ---------------- transpose + fp32->bf16 convert: in[R,C] f32 -> out[C,R] bf16 ----------------
__global__ __launch_bounds__(256) void transpose_cvt_k(const float* __restrict__ in,
                                                       u16* __restrict__ out,
                                                       int R, int C,
                                                       size_t in_stride, size_t out_stride){
  const float* src = in + (size_t)blockIdx.z*in_stride;
  u16* dst = out + (size_t)blockIdx.z*out_stride;
  int tc = blockIdx.x*64;
  int tr = blockIdx.y*64;
  __shared__ float tile[64][65];
  int t=threadIdx.x;
  int lr=t>>4, lc=(t&15)*4;
  #pragma unroll
  for(int i=0;i<4;i++){
    float4 v=*(const float4*)&src[(size_t)(tr+lr+i*16)*C + tc+lc];
    tile[lr+i*16][lc+0]=v.x; tile[lr+i*16][lc+1]=v.y;
    tile[lr+i*16][lc+2]=v.z; tile[lr+i*16][lc+3]=v.w;
  }
  __syncthreads();
  int on=t>>2, kq=(t&3)*16;
  alignas(16) u16 ov[16];
  #pragma unroll
  for(int j=0;j<16;j++) ov[j]=f2bf(tile[kq+j][on]);
  *(uint4*)&dst[(size_t)(tc+on)*R + tr+kq]   = *(uint4*)&ov[0];
  *(uint4*)&dst[(size_t)(tc+on)*R + tr+kq+8] = *(uint4*)&ov[8];
}

// ---------------- V transpose: qkvf[s][2560+kvh*128+d] f32 -> vbT[kvh][d][s] bf16 ----------------
__global__ __launch_bounds__(256) void transpose_v_k(const float* __restrict__ qkvf,
                                                     u16* __restrict__ vbT){
  int st=blockIdx.x*64, dt=blockIdx.y*64, kvh=blockIdx.z;
  __shared__ float tile[64][68];
  int t=threadIdx.x;
  #pragma unroll
  for(int i=0;i<4;i++){
    int f=i*256+t; int sr=f>>4, c4=(f&15)*4;
    float4 v=*(const float4*)&qkvf[(size_t)(st+sr)*3072 + 2560 + kvh*128 + dt + c4];
    tile[sr][c4]=v.x; tile[sr][c4+1]=v.y; tile[sr][c4+2]=v.z; tile[sr][c4+3]=v.w;
  }
  __syncthreads();
  #pragma unroll
  for(int i=0;i<2;i++){
    int f=i*256+t; int dr=f>>3, sc=(f&7)*8;
    alignas(16) u16 ov[8];
    #pragma unroll
    for(int j=0;j<8;j++) ov[j]=f2bf(tile[sc+j][dr]);
    *(uint4*)&vbT[((size_t)kvh*128 + dt+dr)*2048 + st + sc]=*(uint4*)ov;
  }
}

// ---------------- RMSNorm (fp32 in -> bf16 out) ----------------
__global__ __launch_bounds__(256) void rmsnorm_k(const float* __restrict__ x,
                                                 const float* __restrict__ w,
                                                 u16* __restrict__ o){
  int row=blockIdx.x, t=threadIdx.x;
  const float* xr = x + (size_t)row*2048;
  float4 a=*(const float4*)&xr[t*8], b=*(const float4*)&xr[t*8+4];
  float ss = a.x*a.x+a.y*a.y+a.z*a.z+a.w*a.w + b.x*b.x+b.y*b.y+b.z*b.z+b.w*b.w;
  #pragma unroll
  for(int m=1;m<=32;m<<=1) ss += __shfl_xor(ss,m);
  __shared__ float red[4];
  if((t&63)==0) red[t>>6]=ss;
  __syncthreads();
  float tot = red[0]+red[1]+red[2]+red[3];
  float inv = rsqrtf(tot*(1.0f/2048.0f)+1e-6f);
  const float* wr = w + t*8;
  float4 wa=*(const float4*)&wr[0], wb=*(const float4*)&wr[4];
  alignas(16) u16 ov[8];
  ov[0]=f2bf(a.x*inv*wa.x); ov[1]=f2bf(a.y*inv*wa.y);
  ov[2]=f2bf(a.z*inv*wa.z); ov[3]=f2bf(a.w*inv*wa.w);
  ov[4]=f2bf(b.x*inv*wb.x); ov[5]=f2bf(b.y*inv*wb.y);
  ov[6]=f2bf(b.z*inv*wb.z); ov[7]=f2bf(b.w*inv*wb.w);
  *(uint4*)&o[(size_t)row*2048 + t*8] = *(uint4*)ov;
}

// ---------------- Unified B^T GEMM: 64x128 tile, BK=64, dbuf, XCD-chunked swizzle ----------------
template<int MODE>
__global__ __launch_bounds__(256) void gemm_bt_k(const u16* __restrict__ A,
                                                 const u16* __restrict__ BT0,
                                                 const u16* __restrict__ BT1,
                                                 float* __restrict__ Cf,
                                                 u16* __restrict__ Cb,
                                                 const float* __restrict__ hid,
                                                 const int* __restrict__ counts,
                                                 const int* __restrict__ offsets,
                                                 const int* __restrict__ toklist,
                                                 int K, int ldc, int NMT, int NBY){
  __shared__ alignas(16) u16 Al[2][64*64];
  __shared__ alignas(16) u16 Bl[2][128*64];
  __shared__ int slist[64];
  int t=threadIdx.x, lane=t&63, wid=t>>6;
  int nwg=gridDim.x, q=nwg>>3;
  int l=(blockIdx.x&7)*q + (blockIdx.x>>3);
  int e=0, mt, by;
  if constexpr(MODE>=2){
    int per=NMT*NBY;
    e=l/per; int rem=l-e*per;
    mt=(rem%NMT)*64; by=rem/NMT;
  } else {
    mt=(l%NMT)*64; by=l/NMT;
  }
  int cnt=0, off=0;
  if constexpr(MODE>=2){
    cnt=counts[e]; off=offsets[e];
    if(mt>=cnt) return;
  }
  const u16* Bbase;
  int cb=by*128;
  if constexpr(MODE==2){
    if(by<4) Bbase = BT0 + ((size_t)e*512 + by*128)*(size_t)K;
    else     Bbase = BT1 + ((size_t)e*512 + (by-4)*128)*(size_t)K;
  } else if constexpr(MODE==3){
    Bbase = BT0 + ((size_t)e*2048 + (size_t)cb)*(size_t)K;
  } else {
    Bbase = BT0 + (size_t)cb*(size_t)K;
  }
  if constexpr(MODE==2){
    if(t<64){
      int gr=mt+t; if(gr>=cnt) gr=cnt-1;
      slist[t]=toklist[off+gr];
    }
    __syncthreads();
  }
  int srow=t>>3;
  int sc=((t&7)^(srow&7))*8;
  const u16* aptr[2]; const u16* bptr[4];
  #pragma unroll
  for(int i=0;i<2;i++){
    int r=i*32+srow;
    size_t arow;
    if constexpr(MODE==2) arow=(size_t)slist[r];
    else if constexpr(MODE==3){ int s=off+mt+r; if(s>8191)s=8191; arow=(size_t)s; }
    else arow=(size_t)(mt+r);
    aptr[i]=A + arow*(size_t)K + sc;
  }
  #pragma unroll
  for(int i=0;i<4;i++){
    int r=i*32+srow;
    bptr[i]=Bbase + (size_t)r*(size_t)K + sc;
  }
  int fm=lane&15, fo=lane>>4;
  int wm=(wid>>1)*32, wn=(wid&1)*64;
  int aoff[2][2], boff[4][2];
  #pragma unroll
  for(int m=0;m<2;m++){
    int row=wm+m*16+fm;
    #pragma unroll
    for(int kk=0;kk<2;kk++) aoff[m][kk]=row*64 + (((kk*4+fo)^(row&7))*8);
  }
  #pragma unroll
  for(int n=0;n<4;n++){
    int row=wn+n*16+fm;
    #pragma unroll
    for(int kk=0;kk<2;kk++) boff[n][kk]=row*64 + (((kk*4+fo)^(row&7))*8);
  }
  f32x4 acc[2][4];
  #pragma unroll
  for(int m=0;m<2;m++)
    #pragma unroll
    for(int n=0;n<4;n++) acc[m][n]=f4zero();
  int ntk=K>>6;
  #pragma unroll
  for(int i=0;i<2;i++) gld16(aptr[i], &Al[0][i*2048+wid*512]);
  #pragma unroll
  for(int i=0;i<4;i++) gld16(bptr[i], &Bl[0][i*2048+wid*512]);
  __syncthreads();
  for(int kt=0;kt<ntk;kt++){
    int cur=kt&1;
    if(kt+1<ntk){
      int k0=(kt+1)<<6, nb=cur^1;
      #pragma unroll
      for(int i=0;i<2;i++) gld16(aptr[i]+k0, &Al[nb][i*2048+wid*512]);
      #pragma unroll
      for(int i=0;i<4;i++) gld16(bptr[i]+k0, &Bl[nb][i*2048+wid*512]);
    }
    bf16x8 af[2][2], bv[4][2];
    #pragma unroll
    for(int m=0;m<2;m++){
      af[m][0]=*(const bf16x8*)&Al[cur][aoff[m][0]];
      af[m][1]=*(const bf16x8*)&Al[cur][aoff[m][1]];
    }
    #pragma unroll
    for(int n=0;n<4;n++){
      bv[n][0]=*(const bf16x8*)&Bl[cur][boff[n][0]];
      bv[n][1]=*(const bf16x8*)&Bl[cur][boff[n][1]];
    }
    #pragma unroll
    for(int m=0;m<2;m++)
      #pragma unroll
      for(int n=0;n<4;n++){
        acc[m][n]=mfma16(af[m][0],bv[n][0],acc[m][n]);
        acc[m][n]=mfma16(af[m][1],bv[n][1],acc[m][n]);
      }
    __syncthreads();
  }
  #pragma unroll
  for(int m=0;m<2;m++)
    #pragma unroll
    for(int n=0;n<4;n++)
      #pragma unroll
      for(int r=0;r<4;r++){
        int lr=wm+m*16+fo*4+r;
        int col=cb+wn+n*16+fm;
        float v=acc[m][n][r];
        if constexpr(MODE==0){
          Cf[(size_t)(mt+lr)*ldc+col]=v;
        } else if constexpr(MODE==1){
          size_t idx=(size_t)(mt+lr)*ldc+col;
          Cf[idx]=v+hid[idx];
        } else if constexpr(MODE==2){
          int gr=mt+lr;
          if(gr<cnt) Cb[(size_t)(off+gr)*1024+col]=f2bf(v);
        } else {
          int gr=mt+lr;
          if(gr<cnt) Cb[(size_t)(off+gr)*2048+col]=f2bf(v);
        }
      }
}

// ---------------- gather 4 slots per token and add into out ----------------
__global__ __launch_bounds__(256) void moe_reduce_k(const u16* __restrict__ moeb,
                                                    const int* __restrict__ slotof,
                                                    float* __restrict__ out){
  int n=blockIdx.x, t=threadIdx.x;
  int4 s4=*(const int4*)&slotof[n*4];
  int c=t*8;
  const u16* r0=moeb+(size_t)s4.x*2048+c;
  const u16* r1=moeb+(size_t)s4.y*2048+c;
  const u16* r2=moeb+(size_t)s4.z*2048+c;
  const u16* r3=moeb+(size_t)s4.w*2048+c;
  uint4 a=*(const uint4*)r0, b=*(const uint4*)r1,
        cc=*(const uint4*)r2, d=*(const uint4*)r3;
  const u16* pa=(const u16*)&a; const u16* pb=(const u16*)&b;
  const u16* pc=(const u16*)&cc; const u16* pd=(const u16*)&d;
  float* op=out+(size_t)n*2048+c;
  float4 o0=*(const float4*)op, o1=*(const float4*)(op+4);
  float ov[8]={o0.x,o0.y,o0.z,o0.w,o1.x,o1.y,o1.z,o1.w};
  #pragma unroll
  for(int j=0;j<8;j++)
    ov[j]+=bf2f(pa[j])+bf2f(pb[j])+bf2f(pc[j])+bf2f(pd[j]);
  *(float4*)op    =make_float4(ov[0],ov[1],ov[2],ov[3]);
  *(float4*)(op+4)=make_float4(ov[4],ov[5],ov[6],ov[7]);
}

// ---------------- RoPE + pack to bf16 (reads combined qkvf, ld=3072) ----------------
__global__ __launch_bounds__(256) void rope_pack_k(const float* __restrict__ qkvf,
                                                   const float* __restrict__ cosb,
                                                   const float* __restrict__ sinb,
                                                   u16* __restrict__ qb,
                                                   u16* __restrict__ kb){
  int s=blockIdx.x, t=threadIdx.x;
  __shared__ float cs[64], sn[64];
  if(t<64){ cs[t]=cosb[s*64+t]; sn[t]=sinb[s*64+t]; }
  __syncthreads();
  { // Q
    int idx=t*8; int d=idx&127;
    const float* src=qkvf+(size_t)s*3072+idx;
    float4 a=*(const float4*)src, b=*(const float4*)(src+4);
    float v[8]={a.x,a.y,a.z,a.w,b.x,b.y,b.z,b.w};
    alignas(16) u16 o[8];
    if(d<64){
      const float* ps=(d<32)? src+32 : src-32;
      float4 pa=*(const float4*)ps, pb=*(const float4*)(ps+4);
      float p[8]={pa.x,pa.y,pa.z,pa.w,pb.x,pb.y,pb.z,pb.w};
      #pragma unroll
      for(int j=0;j<8;j++){
        float c=cs[d+j], si=sn[d+j];
        float r=(d<32)? (v[j]*c - p[j]*si) : (v[j]*c + p[j]*si);
        o[j]=f2bf(r);
      }
    } else {
      #pragma unroll
      for(int j=0;j<8;j++) o[j]=f2bf(v[j]);
    }
    *(uint4*)&qb[(size_t)s*2048+idx]=*(uint4*)o;
  }
  if(t<64){ // K
    int idx=t*8; int kvh=idx>>7; int d=idx&127;
    const float* src=qkvf+(size_t)s*3072+2048+idx;
    float4 a=*(const float4*)src, b=*(const float4*)(src+4);
    float v[8]={a.x,a.y,a.z,a.w,b.x,b.y,b.z,b.w};
    alignas(16) u16 o[8];
    if(d<64){
      const float* ps=(d<32)? src+32 : src-32;
      float4 pa=*(const float4*)ps, pb=*(const float4*)(ps+4);
      float p[8]={pa.x,pa.y,pa.z,pa.w,pb.x,pb.y,pb.z,pb.w};
      #pragma unroll
      for(int j=0;j<8;j++){
        float c=cs[d+j], si=sn[d+j];
        float r=(d<32)? (v[j]*c - p[j]*si) : (v[j]*c + p[j]*si);
        o[j]=f2bf(r);
      }
    } else {
      #pragma unroll
      for(int j=0;j<8;j++) o[j]=f2bf(v[j]);
    }
    *(uint4*)&kb[((size_t)kvh*SEQ + s)*128 + d]=*(uint4*)o;
  }
}

// ---------------- Flash attention: QBLK=64, KVBLK=64, dbuf gld16 staging (r8 form) ----------------
// + T13 defer-max (ISOLATED this round): skip the O-rescale while the tile max stays
//   within +8 of the running max (P bounded by e^8; final normalization uses true max).
__global__ __launch_bounds__(256) void attn_k(const u16* __restrict__ qb,
                                              const u16* __restrict__ kb,
                                              const u16* __restrict__ vbT,
                                              const float* __restrict__ sink,
                                              u16* __restrict__ ao){
  int h=blockIdx.x;
  int qt=31-blockIdx.y;
  int kvh=h>>2;
  int t=threadIdx.x, wid=t>>6, lane=t&63;
  int fm=lane&15, fo=lane>>4;
  int qbase=qt*64;
  __shared__ alignas(16) u16 Kl[2][64*128];
  __shared__ alignas(16) u16 Vl[2][128*64];
  __shared__ alignas(16) u16 Pl[4][16*72];
  bf16x8 qfr[4];
  int qrow=qbase+wid*16+fm;
  #pragma unroll
  for(int c=0;c<4;c++)
    qfr[c]=*(const bf16x8*)&qb[(size_t)qrow*2048 + h*128 + c*32 + fo*8];
  f32x4 o[8];
  #pragma unroll
  for(int dg=0;dg<8;dg++) o[dg]=f4zero();
  float mr[4]={-1e30f,-1e30f,-1e30f,-1e30f};
  float ls[4]={0.f,0.f,0.f,0.f};
  const u16* kbase=kb+(size_t)kvh*SEQ*128;
  const u16* vtb=vbT+(size_t)kvh*128*SEQ;
  int nt=qt+1;
  u16* pw=&Pl[wid][0];
  {
    #pragma unroll
    for(int i=0;i<4;i++){
      int fc=(wid*4+i)*64+lane;
      int row=fc>>4, g=(fc&15)^(row&15);
      gld16(kbase+(size_t)row*128+g*8, &Kl[0][(wid*4+i)*512]);
    }
    #pragma unroll
    for(int i=0;i<4;i++){
      int fc=(wid*4+i)*64+lane;
      int row=fc>>3, g=(fc&7)^(row&7);
      gld16(vtb+(size_t)row*2048+g*8, &Vl[0][(wid*4+i)*512]);
    }
  }
  __syncthreads();
  for(int tt=0;tt<nt;tt++){
    int cur=tt&1;
    if(tt+1<nt){
      int kv0n=(tt+1)*64, nb=cur^1;
      #pragma unroll
      for(int i=0;i<4;i++){
        int fc=(wid*4+i)*64+lane;
        int row=fc>>4, g=(fc&15)^(row&15);
        gld16(kbase+(size_t)(kv0n+row)*128+g*8, &Kl[nb][(wid*4+i)*512]);
      }
      #pragma unroll
      for(int i=0;i<4;i++){
        int fc=(wid*4+i)*64+lane;
        int row=fc>>3, g=(fc&7)^(row&7);
        gld16(vtb+(size_t)row*2048+kv0n+g*8, &Vl[nb][(wid*4+i)*512]);
      }
    }
    int kv0=tt*64;
    f32x4 s[4];
    #pragma unroll
    for(int ss=0;ss<4;ss++) s[ss]=f4zero();
    #pragma unroll
    for(int c=0;c<4;c++){
      #pragma unroll
      for(int ss=0;ss<4;ss++){
        int row=ss*16+fm;
        bf16x8 kf=*(const bf16x8*)&Kl[cur][row*128 + (((c*4+fo)^(row&15))*8)];
        s[ss]=mfma16(qfr[c],kf,s[ss]);
      }
    }
    bool diag=(tt==nt-1);
    int qg=qbase+wid*16+fo*4;
    #pragma unroll
    for(int r=0;r<4;r++){
      float v0=s[0][r]*ATT_SCALE, v1=s[1][r]*ATT_SCALE,
            v2=s[2][r]*ATT_SCALE, v3=s[3][r]*ATT_SCALE;
      if(diag){
        int qr=qg+r;
        if(kv0+   fm > qr) v0=-1e30f;
        if(kv0+16+fm > qr) v1=-1e30f;
        if(kv0+32+fm > qr) v2=-1e30f;
        if(kv0+48+fm > qr) v3=-1e30f;
      }
      float vm=fmaxf(fmaxf(v0,v1),fmaxf(v2,v3));
      vm=fmaxf(vm,__shfl_xor(vm,1)); vm=fmaxf(vm,__shfl_xor(vm,2));
      vm=fmaxf(vm,__shfl_xor(vm,4)); vm=fmaxf(vm,__shfl_xor(vm,8));
      // T13 defer-max: rescale only when the tile max exceeds the +8 slack.
      if(__any(vm > mr[r] + 8.0f)){
        float mn=fmaxf(mr[r],vm);
        float sc=__expf(mr[r]-mn);
        mr[r]=mn;
        ls[r]*=sc;
        #pragma unroll
        for(int dg=0;dg<8;dg++) o[dg][r]*=sc;
      }
      float p0=__expf(v0-mr[r]), p1=__expf(v1-mr[r]),
            p2=__expf(v2-mr[r]), p3=__expf(v3-mr[r]);
      float rs=(p0+p1)+(p2+p3);
      rs+=__shfl_xor(rs,1); rs+=__shfl_xor(rs,2);
      rs+=__shfl_xor(rs,4); rs+=__shfl_xor(rs,8);
      ls[r]+=rs;
      int prow=(fo*4+r)*72;
      pw[prow+fm   ]=f2bf(p0);
      pw[prow+16+fm]=f2bf(p1);
      pw[prow+32+fm]=f2bf(p2);
      pw[prow+48+fm]=f2bf(p3);
    }
    #pragma unroll
    for(int kvs=0;kvs<2;kvs++){
      bf16x8 pa=*(const bf16x8*)&pw[fm*72 + kvs*32 + fo*8];
      #pragma unroll
      for(int dg=0;dg<8;dg++){
        int R=dg*16+fm;
        bf16x8 bv=*(const bf16x8*)&Vl[cur][R*64 + (((kvs*4+fo)^(R&7))*8)];
        o[dg]=mfma16(pa,bv,o[dg]);
      }
    }
    __syncthreads();
  }
  float sb=sink[h];
  float invd[4];
  #pragma unroll
  for(int r=0;r<4;r++) invd[r]=1.f/(ls[r]+__expf(sb-mr[r]));
  #pragma unroll
  for(int dg=0;dg<8;dg++)
    #pragma unroll
    for(int r=0;r<4;r++){
      int row=qbase+wid*16+fo*4+r;
      ao[(size_t)row*2048 + h*128 + dg*16 + fm]=f2bf(o[dg][r]*invd[r]);
    }
}

// ---------------- Fused RMSNorm + gate logits + routing ----------------
__global__ __launch_bounds__(256) void gate_route_k(const float* __restrict__ h1,
                                                    const float* __restrict__ lnw,
                                                    const float* __restrict__ gw,
                                                    const float* __restrict__ gb,
                                                    int* __restrict__ tsel,
                                                    float* __restrict__ twsel){
  int n=blockIdx.x, t=threadIdx.x, lane=t&63, wid=t>>6;
  const float* xr=h1+(size_t)n*2048;
  float4 a=*(const float4*)&xr[t*8], b=*(const float4*)&xr[t*8+4];
  float xv[8]={a.x,a.y,a.z,a.w,b.x,b.y,b.z,b.w};
  float ss=0.f;
  #pragma unroll
  for(int j=0;j<8;j++) ss+=xv[j]*xv[j];
  #pragma unroll
  for(int m=1;m<=32;m<<=1) ss+=__shfl_xor(ss,m);
  __shared__ float redn[4];
  if(lane==0) redn[wid]=ss;
  __syncthreads();
  float inv=rsqrtf((redn[0]+redn[1]+redn[2]+redn[3])*(1.0f/2048.0f)+1e-6f);
  const float* wr=lnw+t*8;
  float4 wa=*(const float4*)&wr[0], wb=*(const float4*)&wr[4];
  float wv[8]={wa.x,wa.y,wa.z,wa.w,wb.x,wb.y,wb.z,wb.w};
  #pragma unroll
  for(int j=0;j<8;j++) xv[j]*=inv*wv[j];
  float part[16];
  #pragma unroll
  for(int e=0;e<16;e++){
    const float* g=gw+(size_t)e*2048+t*8;
    float4 ga=*(const float4*)&g[0], gb2=*(const float4*)&g[4];
    part[e]=xv[0]*ga.x+xv[1]*ga.y+xv[2]*ga.z+xv[3]*ga.w
           +xv[4]*gb2.x+xv[5]*gb2.y+xv[6]*gb2.z+xv[7]*gb2.w;
  }
  #pragma unroll
  for(int e=0;e<16;e++)
    #pragma unroll
    for(int m=1;m<=32;m<<=1) part[e]+=__shfl_xor(part[e],m);
  __shared__ float red[4][16];
  __shared__ float lg[16];
  if(lane<16) red[wid][lane]=part[lane];
  __syncthreads();
  if(t<16) lg[t]=red[0][t]+red[1][t]+red[2][t]+red[3][t];
  __syncthreads();
  if(t==0){
    float sg[16], sfc[16];
    #pragma unroll
    for(int e=0;e<16;e++){ sg[e]=1.f/(1.f+__expf(-lg[e])); sfc[e]=sg[e]+gb[e]; }
    float gs[4];
    #pragma unroll
    for(int g=0;g<4;g++){
      const float* v=&sfc[g*4];
      int im=0;
      for(int j=1;j<4;j++) if(v[j]>v[im]) im=j;
      float m2=-1e30f;
      for(int j=0;j<4;j++) if(j!=im && v[j]>m2) m2=v[j];
      gs[g]=v[im]+m2;
    }
    int g1=0;
    for(int j=1;j<4;j++) if(gs[j]>gs[g1]) g1=j;
    int g2=-1;
    for(int j=0;j<4;j++){ if(j==g1) continue; if(g2<0||gs[j]>gs[g2]) g2=j; }
    bool used[16];
    for(int e=0;e<16;e++) used[e]=false;
    int ch[4]; float tw[4];
    for(int s=0;s<4;s++){
      int best=-1; float bvv=-1e30f;
      for(int e=0;e<16;e++){
        int g=e>>2;
        if(g!=g1 && g!=g2) continue;
        if(used[e]) continue;
        if(sfc[e]>bvv){ bvv=sfc[e]; best=e; }
      }
      used[best]=true; ch[s]=best; tw[s]=sg[best];
    }
    float ssum=tw[0]+tw[1]+tw[2]+tw[3]+1e-20f;
    float sc=2.5f/ssum;
    for(int s=0;s<4;s++){ tsel[n*4+s]=ch[s]; twsel[n*4+s]=tw[s]*sc; }
  }
}

// ---------------- histogram + scan + compact per-expert token lists ----------------
__global__ __launch_bounds__(256) void scan_fill_k(const int* __restrict__ tsel,
                                                   const float* __restrict__ twsel,
                                                   int* __restrict__ counts,
                                                   int* __restrict__ offsets,
                                                   int* __restrict__ toklist,
                                                   float* __restrict__ wslot,
                                                   int* __restrict__ slotof){
  __shared__ int cnt[16], off[16], cur[16];
  int t=threadIdx.x;
  if(t<16){ cnt[t]=0; cur[t]=0; }
  __syncthreads();
  for(int n=t;n<2048;n+=256)
    for(int j=0;j<4;j++) atomicAdd(&cnt[tsel[n*4+j]],1);
  __syncthreads();
  if(t==0){
    int run=0;
    for(int e=0;e<16;e++){ off[e]=run; run+=cnt[e]; }
  }
  __syncthreads();
  if(t<16){ counts[t]=cnt[t]; offsets[t]=off[t]; }
  for(int n=t;n<2048;n+=256)
    for(int j=0;j<4;j++){
      int e=tsel[n*4+j];
      int pos=atomicAdd(&cur[e],1);
      int slot=off[e]+pos;
      toklist[slot]=n;
      wslot[slot]=twsel[n*4+j];
      slotof[n*4+j]=slot;
    }
}

// ---------------- hgu = silu(g)*u*w ----------------
__global__ __launch_bounds__(256) void hgu_act_k(const u16* __restrict__ gu,
                                                 const float* __restrict__ wslot,
                                                 u16* __restrict__ hgu){
  int t=threadIdx.x;
  int slot=blockIdx.x*4+(t>>6);
  int f8=(t&63)*8;
  float wv=wslot[slot];
  uint4 gr=*(const uint4*)&gu[(size_t)slot*1024+f8];
  uint4 ur=*(const uint4*)&gu[(size_t)slot*1024+512+f8];
  const u16* gp=(const u16*)&gr;
  const u16* up=(const u16*)&ur;
  alignas(16) u16 o[8];
  #pragma unroll
  for(int j=0;j<8;j++){
    float g=bf2f(gp[j]), u=bf2f(up[j]);
    float s=g/(1.f+__expf(-g));
    o[j]=f2bf(s*u*wv);
  }
  *(uint4*)&hgu[(size_t)slot*512+f8]=*(uint4*)o;
}

extern "C" void kernel_launch(void* const* d_in, const int* in_sizes, int n_in,
                              void* d_out, int out_size, void* d_ws, size_t ws_size,
                              hipStream_t stream){
  const float* x    =(const float*)d_in[0];
  const float* cosb =(const float*)d_in[1];
  const float* sinb =(const float*)d_in[2];
  const float* ln1w =(const float*)d_in[3];
  const float* ln2w =(const float*)d_in[4];
  const float* Wq   =(const float*)d_in[5];
  const float* Wk   =(const float*)d_in[6];
  const float* Wv   =(const float*)d_in[7];
  const float* Wo   =(const float*)d_in[8];
  const float* sink =(const float*)d_in[9];
  const float* gw   =(const float*)d_in[10];
  const float* gb   =(const float*)d_in[11];
  const float* Weg  =(const float*)d_in[12];
  const float* Weu  =(const float*)d_in[13];
  const float* Wed  =(const float*)d_in[14];
  float* out=(float*)d_out;
  char* w=(char*)d_ws;
  const size_t MB=1024*1024;
  float* qkvf=(float*)(w+0);        // 24MB [2048][3072] ; later gu/hgu alias
  u16* gu =(u16*)(w+0);             // 16MB
  u16* hgu=(u16*)(w+16*MB);         // 8MB
  u16* xn =(u16*)(w+24*MB);         // 8MB
  u16* qb =(u16*)(w+32*MB);         // 8MB
  u16* kb =(u16*)(w+40*MB);         // 2MB
  u16* vbT=(u16*)(w+42*MB);         // 2MB [4][128][2048]
  u16* aob=(u16*)(w+44*MB);         // 8MB
  u16* xfb=(u16*)(w+52*MB);         // 8MB
  int*   tsel   =(int*)(w+60*MB);
  float* twsel  =(float*)(w+60*MB+32768);
  int*   counts =(int*)(w+60*MB+65536);
  int*   offsets=(int*)(w+60*MB+65536+256);
  int*   toklist=(int*)(w+60*MB+65536+512);
  float* wslot  =(float*)(w+60*MB+65536+512+32768);
  int*   slotof =(int*)(w+60*MB+65536+512+65536);
  char* wt=w+61*MB;
  u16* WqT=(u16*)(wt);              // 8MB  } contiguous ->
  u16* WkT=(u16*)(wt+8*MB);         // 2MB  }  one [3072][2048] B^T
  u16* WvT=(u16*)(wt+10*MB);        // 2MB  }
  u16* WoT=(u16*)(wt+12*MB);        // 8MB (ends 81MB)
  u16* WegT=(u16*)(wt);             // 32MB (after Wo gemm; dead after moe gemm1)
  u16* WeuT=(u16*)(wt+32*MB);       // 32MB (dead after moe gemm1; ends 125MB)
  u16* WedT=(u16*)(wt);             // 32MB (written after moe gemm1, over WegT)
  u16* moeb=(u16*)(wt+32*MB);       // 32MB slot-major moe output (over dead WeuT)

  dim3 blk(256);
  transpose_cvt_k<<<dim3(32,32,1),blk,0,stream>>>(Wq, WqT, 2048,2048, 0,0);
  transpose_cvt_k<<<dim3(8,32,1), blk,0,stream>>>(Wk, WkT, 2048,512, 0,0);
  transpose_cvt_k<<<dim3(8,32,1), blk,0,stream>>>(Wv, WvT, 2048,512, 0,0);
  transpose_cvt_k<<<dim3(32,32,1),blk,0,stream>>>(Wo, WoT, 2048,2048, 0,0);
  rmsnorm_k<<<dim3(2048),blk,0,stream>>>(x, ln1w, xn);
  gemm_bt_k<0><<<dim3(768),blk,0,stream>>>(xn, WqT,nullptr, qkvf,nullptr,nullptr,
                                           nullptr,nullptr,nullptr, 2048,3072, 32,24);
  rope_pack_k<<<dim3(2048),blk,0,stream>>>(qkvf,cosb,sinb,qb,kb);
  transpose_v_k<<<dim3(32,2,4),blk,0,stream>>>(qkvf, vbT);
  attn_k<<<dim3(16,32),blk,0,stream>>>(qb,kb,vbT,sink,aob);
  gemm_bt_k<1><<<dim3(512),blk,0,stream>>>(aob, WoT,nullptr, out,nullptr,x,
                                           nullptr,nullptr,nullptr, 2048,2048, 32,16);
  rmsnorm_k<<<dim3(2048),blk,0,stream>>>(out, ln2w, xfb);
  gate_route_k<<<dim3(2048),blk,0,stream>>>(out, ln2w, gw, gb, tsel, twsel);
  scan_fill_k<<<dim3(1),blk,0,stream>>>(tsel, twsel, counts, offsets, toklist, wslot, slotof);
  transpose_cvt_k<<<dim3(8,32,16),blk,0,stream>>>(Weg, WegT, 2048,512, 1048576,1048576);
  transpose_cvt_k<<<dim3(8,32,16),blk,0,stream>>>(Weu, WeuT, 2048,512, 1048576,1048576);
  gemm_bt_k<2><<<dim3(4096),blk,0,stream>>>(xfb, WegT,WeuT, nullptr,gu,nullptr,
                                            counts,offsets,toklist, 2048,1024, 32,8);
  hgu_act_k<<<dim3(2048),blk,0,stream>>>(gu, wslot, hgu);
  transpose_cvt_k<<<dim3(32,8,16),blk,0,stream>>>(Wed, WedT, 512,2048, 1048576,1048576);
  gemm_bt_k<3><<<dim3(8192),blk,0,stream>>>(hgu, WedT,nullptr, nullptr,moeb,nullptr,
                                            counts,offsets,toklist, 512,2048, 32,16);
  moe_reduce_k<<<dim3(2048),blk,0,stream>>>(moeb, slotof, out);
}

// Round 13
// 389.999 us; speedup vs baseline: 1.0261x; 1.0261x over previous
//
#include <hip/hip_runtime.h>
#include <math.h>

typedef unsigned short u16;
typedef __bf16 bf16x8 __attribute__((ext_vector_type(8)));
typedef float f32x4 __attribute__((ext_vector_type(4)));

#define SEQ 2048
#define ATT_SCALE 0.08838834764831845f

__device__ __forceinline__ u16 f2bf(float f){
  union{float f;unsigned u;}v; v.f=f;
  unsigned r=v.u + 0x7fffu + ((v.u>>16)&1u);
  return (u16)(r>>16);
}
__device__ __forceinline__ float bf2f(u16 u){
  union{unsigned u;float f;}v; v.u=((unsigned)u)<<16; return v.f;
}
__device__ __forceinline__ f32x4 f4zero(){ f32x4 v; v[0]=0.f;v[1]=0.f;v[2]=0.f;v[3]=0.f; return v; }
__device__ __forceinline__ f32x4 mfma16(bf16x8 a, bf16x8 b, f32x4 c){
  return __builtin_amdgcn_mfma_f32_16x16x32_bf16(a,b,c,0,0,0);
}

typedef const __attribute__((address_space(1))) unsigned char* gas1p;
typedef __attribute__((address_space(3))) unsigned char* las3p;
__device__ __forceinline__ void gld16(const void* g, void* l){
  __builtin_amdgcn_global_load_lds((gas1p)g, (las3p)l, 16, 0, 0);
}

// ---------------- transpose + fp32->bf16 convert: in[R,C] f32 -> out[C,R] bf16 ----------------
__global__ __launch_bounds__(256) void transpose_cvt_k(const float* __restrict__ in,
                                                       u16* __restrict__ out,
                                                       int R, int C,
                                                       size_t in_stride, size_t out_stride){
  const float* src = in + (size_t)blockIdx.z*in_stride;
  u16* dst = out + (size_t)blockIdx.z*out_stride;
  int tc = blockIdx.x*64;
  int tr = blockIdx.y*64;
  __shared__ float tile[64][65];
  int t=threadIdx.x;
  int lr=t>>4, lc=(t&15)*4;
  #pragma unroll
  for(int i=0;i<4;i++){
    float4 v=*(const float4*)&src[(size_t)(tr+lr+i*16)*C + tc+lc];
    tile[lr+i*16][lc+0]=v.x; tile[lr+i*16][lc+1]=v.y;
    tile[lr+i*16][lc+2]=v.z; tile[lr+i*16][lc+3]=v.w;
  }
  __syncthreads();
  int on=t>>2, kq=(t&3)*16;
  alignas(16) u16 ov[16];
  #pragma unroll
  for(int j=0;j<16;j++) ov[j]=f2bf(tile[kq+j][on]);
  *(uint4*)&dst[(size_t)(tc+on)*R + tr+kq]   = *(uint4*)&ov[0];
  *(uint4*)&dst[(size_t)(tc+on)*R + tr+kq+8] = *(uint4*)&ov[8];
}

// ---------------- V transpose: qkvf[s][2560+kvh*128+d] f32 -> vbT[kvh][d][s] bf16 ----------------
__global__ __launch_bounds__(256) void transpose_v_k(const float* __restrict__ qkvf,
                                                     u16* __restrict__ vbT){
  int st=blockIdx.x*64, dt=blockIdx.y*64, kvh=blockIdx.z;
  __shared__ float tile[64][68];
  int t=threadIdx.x;
  #pragma unroll
  for(int i=0;i<4;i++){
    int f=i*256+t; int sr=f>>4, c4=(f&15)*4;
    float4 v=*(const float4*)&qkvf[(size_t)(st+sr)*3072 + 2560 + kvh*128 + dt + c4];
    tile[sr][c4]=v.x; tile[sr][c4+1]=v.y; tile[sr][c4+2]=v.z; tile[sr][c4+3]=v.w;
  }
  __syncthreads();
  #pragma unroll
  for(int i=0;i<2;i++){
    int f=i*256+t; int dr=f>>3, sc=(f&7)*8;
    alignas(16) u16 ov[8];
    #pragma unroll
    for(int j=0;j<8;j++) ov[j]=f2bf(tile[sc+j][dr]);
    *(uint4*)&vbT[((size_t)kvh*128 + dt+dr)*2048 + st + sc]=*(uint4*)ov;
  }
}

// ---------------- RMSNorm (fp32 in -> bf16 out) ----------------
__global__ __launch_bounds__(256) void rmsnorm_k(const float* __restrict__ x,
                                                 const float* __restrict__ w,
                                                 u16* __restrict__ o){
  int row=blockIdx.x, t=threadIdx.x;
  const float* xr = x + (size_t)row*2048;
  float4 a=*(const float4*)&xr[t*8], b=*(const float4*)&xr[t*8+4];
  float ss = a.x*a.x+a.y*a.y+a.z*a.z+a.w*a.w + b.x*b.x+b.y*b.y+b.z*b.z+b.w*b.w;
  #pragma unroll
  for(int m=1;m<=32;m<<=1) ss += __shfl_xor(ss,m);
  __shared__ float red[4];
  if((t&63)==0) red[t>>6]=ss;
  __syncthreads();
  float tot = red[0]+red[1]+red[2]+red[3];
  float inv = rsqrtf(tot*(1.0f/2048.0f)+1e-6f);
  const float* wr = w + t*8;
  float4 wa=*(const float4*)&wr[0], wb=*(const float4*)&wr[4];
  alignas(16) u16 ov[8];
  ov[0]=f2bf(a.x*inv*wa.x); ov[1]=f2bf(a.y*inv*wa.y);
  ov[2]=f2bf(a.z*inv*wa.z); ov[3]=f2bf(a.w*inv*wa.w);
  ov[4]=f2bf(b.x*inv*wb.x); ov[5]=f2bf(b.y*inv*wb.y);
  ov[6]=f2bf(b.z*inv*wb.z); ov[7]=f2bf(b.w*inv*wb.w);
  *(uint4*)&o[(size_t)row*2048 + t*8] = *(uint4*)ov;
}

// ---------------- Unified B^T GEMM: 64x128 tile, BK=64, dbuf, XCD-chunked swizzle ----------------
template<int MODE>
__global__ __launch_bounds__(256) void gemm_bt_k(const u16* __restrict__ A,
                                                 const u16* __restrict__ BT0,
                                                 const u16* __restrict__ BT1,
                                                 float* __restrict__ Cf,
                                                 u16* __restrict__ Cb,
                                                 const float* __restrict__ hid,
                                                 const int* __restrict__ counts,
                                                 const int* __restrict__ offsets,
                                                 const int* __restrict__ toklist,
                                                 int K, int ldc, int NMT, int NBY){
  __shared__ alignas(16) u16 Al[2][64*64];
  __shared__ alignas(16) u16 Bl[2][128*64];
  __shared__ int slist[64];
  int t=threadIdx.x, lane=t&63, wid=t>>6;
  int nwg=gridDim.x, q=nwg>>3;
  int l=(blockIdx.x&7)*q + (blockIdx.x>>3);
  int e=0, mt, by;
  if constexpr(MODE>=2){
    int per=NMT*NBY;
    e=l/per; int rem=l-e*per;
    mt=(rem%NMT)*64; by=rem/NMT;
  } else {
    mt=(l%NMT)*64; by=l/NMT;
  }
  int cnt=0, off=0;
  if constexpr(MODE>=2){
    cnt=counts[e]; off=offsets[e];
    if(mt>=cnt) return;
  }
  const u16* Bbase;
  int cb=by*128;
  if constexpr(MODE==2){
    if(by<4) Bbase = BT0 + ((size_t)e*512 + by*128)*(size_t)K;
    else     Bbase = BT1 + ((size_t)e*512 + (by-4)*128)*(size_t)K;
  } else if constexpr(MODE==3){
    Bbase = BT0 + ((size_t)e*2048 + (size_t)cb)*(size_t)K;
  } else {
    Bbase = BT0 + (size_t)cb*(size_t)K;
  }
  if constexpr(MODE==2){
    if(t<64){
      int gr=mt+t; if(gr>=cnt) gr=cnt-1;
      slist[t]=toklist[off+gr];
    }
    __syncthreads();
  }
  int srow=t>>3;
  int sc=((t&7)^(srow&7))*8;
  const u16* aptr[2]; const u16* bptr[4];
  #pragma unroll
  for(int i=0;i<2;i++){
    int r=i*32+srow;
    size_t arow;
    if constexpr(MODE==2) arow=(size_t)slist[r];
    else if constexpr(MODE==3){ int s=off+mt+r; if(s>8191)s=8191; arow=(size_t)s; }
    else arow=(size_t)(mt+r);
    aptr[i]=A + arow*(size_t)K + sc;
  }
  #pragma unroll
  for(int i=0;i<4;i++){
    int r=i*32+srow;
    bptr[i]=Bbase + (size_t)r*(size_t)K + sc;
  }
  int fm=lane&15, fo=lane>>4;
  int wm=(wid>>1)*32, wn=(wid&1)*64;
  int aoff[2][2], boff[4][2];
  #pragma unroll
  for(int m=0;m<2;m++){
    int row=wm+m*16+fm;
    #pragma unroll
    for(int kk=0;kk<2;kk++) aoff[m][kk]=row*64 + (((kk*4+fo)^(row&7))*8);
  }
  #pragma unroll
  for(int n=0;n<4;n++){
    int row=wn+n*16+fm;
    #pragma unroll
    for(int kk=0;kk<2;kk++) boff[n][kk]=row*64 + (((kk*4+fo)^(row&7))*8);
  }
  f32x4 acc[2][4];
  #pragma unroll
  for(int m=0;m<2;m++)
    #pragma unroll
    for(int n=0;n<4;n++) acc[m][n]=f4zero();
  int ntk=K>>6;
  #pragma unroll
  for(int i=0;i<2;i++) gld16(aptr[i], &Al[0][i*2048+wid*512]);
  #pragma unroll
  for(int i=0;i<4;i++) gld16(bptr[i], &Bl[0][i*2048+wid*512]);
  __syncthreads();
  for(int kt=0;kt<ntk;kt++){
    int cur=kt&1;
    if(kt+1<ntk){
      int k0=(kt+1)<<6, nb=cur^1;
      #pragma unroll
      for(int i=0;i<2;i++) gld16(aptr[i]+k0, &Al[nb][i*2048+wid*512]);
      #pragma unroll
      for(int i=0;i<4;i++) gld16(bptr[i]+k0, &Bl[nb][i*2048+wid*512]);
    }
    bf16x8 af[2][2], bv[4][2];
    #pragma unroll
    for(int m=0;m<2;m++){
      af[m][0]=*(const bf16x8*)&Al[cur][aoff[m][0]];
      af[m][1]=*(const bf16x8*)&Al[cur][aoff[m][1]];
    }
    #pragma unroll
    for(int n=0;n<4;n++){
      bv[n][0]=*(const bf16x8*)&Bl[cur][boff[n][0]];
      bv[n][1]=*(const bf16x8*)&Bl[cur][boff[n][1]];
    }
    #pragma unroll
    for(int m=0;m<2;m++)
      #pragma unroll
      for(int n=0;n<4;n++){
        acc[m][n]=mfma16(af[m][0],bv[n][0],acc[m][n]);
        acc[m][n]=mfma16(af[m][1],bv[n][1],acc[m][n]);
      }
    __syncthreads();
  }
  #pragma unroll
  for(int m=0;m<2;m++)
    #pragma unroll
    for(int n=0;n<4;n++)
      #pragma unroll
      for(int r=0;r<4;r++){
        int lr=wm+m*16+fo*4+r;
        int col=cb+wn+n*16+fm;
        float v=acc[m][n][r];
        if constexpr(MODE==0){
          Cf[(size_t)(mt+lr)*ldc+col]=v;
        } else if constexpr(MODE==1){
          size_t idx=(size_t)(mt+lr)*ldc+col;
          Cf[idx]=v+hid[idx];
        } else if constexpr(MODE==2){
          int gr=mt+lr;
          if(gr<cnt) Cb[(size_t)(off+gr)*1024+col]=f2bf(v);
        } else {
          int gr=mt+lr;
          if(gr<cnt) Cb[(size_t)(off+gr)*2048+col]=f2bf(v);
        }
      }
}

// ---------------- gather 4 slots per token and add into out ----------------
__global__ __launch_bounds__(256) void moe_reduce_k(const u16* __restrict__ moeb,
                                                    const int* __restrict__ slotof,
                                                    float* __restrict__ out){
  int n=blockIdx.x, t=threadIdx.x;
  int4 s4=*(const int4*)&slotof[n*4];
  int c=t*8;
  const u16* r0=moeb+(size_t)s4.x*2048+c;
  const u16* r1=moeb+(size_t)s4.y*2048+c;
  const u16* r2=moeb+(size_t)s4.z*2048+c;
  const u16* r3=moeb+(size_t)s4.w*2048+c;
  uint4 a=*(const uint4*)r0, b=*(const uint4*)r1,
        cc=*(const uint4*)r2, d=*(const uint4*)r3;
  const u16* pa=(const u16*)&a; const u16* pb=(const u16*)&b;
  const u16* pc=(const u16*)&cc; const u16* pd=(const u16*)&d;
  float* op=out+(size_t)n*2048+c;
  float4 o0=*(const float4*)op, o1=*(const float4*)(op+4);
  float ov[8]={o0.x,o0.y,o0.z,o0.w,o1.x,o1.y,o1.z,o1.w};
  #pragma unroll
  for(int j=0;j<8;j++)
    ov[j]+=bf2f(pa[j])+bf2f(pb[j])+bf2f(pc[j])+bf2f(pd[j]);
  *(float4*)op    =make_float4(ov[0],ov[1],ov[2],ov[3]);
  *(float4*)(op+4)=make_float4(ov[4],ov[5],ov[6],ov[7]);
}

// ---------------- RoPE + pack to bf16 (reads combined qkvf, ld=3072) ----------------
__global__ __launch_bounds__(256) void rope_pack_k(const float* __restrict__ qkvf,
                                                   const float* __restrict__ cosb,
                                                   const float* __restrict__ sinb,
                                                   u16* __restrict__ qb,
                                                   u16* __restrict__ kb){
  int s=blockIdx.x, t=threadIdx.x;
  __shared__ float cs[64], sn[64];
  if(t<64){ cs[t]=cosb[s*64+t]; sn[t]=sinb[s*64+t]; }
  __syncthreads();
  { // Q
    int idx=t*8; int d=idx&127;
    const float* src=qkvf+(size_t)s*3072+idx;
    float4 a=*(const float4*)src, b=*(const float4*)(src+4);
    float v[8]={a.x,a.y,a.z,a.w,b.x,b.y,b.z,b.w};
    alignas(16) u16 o[8];
    if(d<64){
      const float* ps=(d<32)? src+32 : src-32;
      float4 pa=*(const float4*)ps, pb=*(const float4*)(ps+4);
      float p[8]={pa.x,pa.y,pa.z,pa.w,pb.x,pb.y,pb.z,pb.w};
      #pragma unroll
      for(int j=0;j<8;j++){
        float c=cs[d+j], si=sn[d+j];
        float r=(d<32)? (v[j]*c - p[j]*si) : (v[j]*c + p[j]*si);
        o[j]=f2bf(r);
      }
    } else {
      #pragma unroll
      for(int j=0;j<8;j++) o[j]=f2bf(v[j]);
    }
    *(uint4*)&qb[(size_t)s*2048+idx]=*(uint4*)o;
  }
  if(t<64){ // K
    int idx=t*8; int kvh=idx>>7; int d=idx&127;
    const float* src=qkvf+(size_t)s*3072+2048+idx;
    float4 a=*(const float4*)src, b=*(const float4*)(src+4);
    float v[8]={a.x,a.y,a.z,a.w,b.x,b.y,b.z,b.w};
    alignas(16) u16 o[8];
    if(d<64){
      const float* ps=(d<32)? src+32 : src-32;
      float4 pa=*(const float4*)ps, pb=*(const float4*)(ps+4);
      float p[8]={pa.x,pa.y,pa.z,pa.w,pb.x,pb.y,pb.z,pb.w};
      #pragma unroll
      for(int j=0;j<8;j++){
        float c=cs[d+j], si=sn[d+j];
        float r=(d<32)? (v[j]*c - p[j]*si) : (v[j]*c + p[j]*si);
        o[j]=f2bf(r);
      }
    } else {
      #pragma unroll
      for(int j=0;j<8;j++) o[j]=f2bf(v[j]);
    }
    *(uint4*)&kb[((size_t)kvh*SEQ + s)*128 + d]=*(uint4*)o;
  }
}

// ---------------- Flash attention: QBLK=64, KVBLK=64, dbuf gld16 staging (r6 best-known) ----------------
__global__ __launch_bounds__(256) void attn_k(const u16* __restrict__ qb,
                                              const u16* __restrict__ kb,
                                              const u16* __restrict__ vbT,
                                              const float* __restrict__ sink,
                                              u16* __restrict__ ao){
  int h=blockIdx.x;
  int qt=31-blockIdx.y;
  int kvh=h>>2;
  int t=threadIdx.x, wid=t>>6, lane=t&63;
  int fm=lane&15, fo=lane>>4;
  int qbase=qt*64;
  __shared__ alignas(16) u16 Kl[2][64*128];
  __shared__ alignas(16) u16 Vl[2][128*64];
  __shared__ alignas(16) u16 Pl[4][16*72];
  bf16x8 qfr[4];
  int qrow=qbase+wid*16+fm;
  #pragma unroll
  for(int c=0;c<4;c++)
    qfr[c]=*(const bf16x8*)&qb[(size_t)qrow*2048 + h*128 + c*32 + fo*8];
  f32x4 o[8];
  #pragma unroll
  for(int dg=0;dg<8;dg++) o[dg]=f4zero();
  float mr[4]={-1e30f,-1e30f,-1e30f,-1e30f};
  float ls[4]={0.f,0.f,0.f,0.f};
  const u16* kbase=kb+(size_t)kvh*SEQ*128;
  const u16* vtb=vbT+(size_t)kvh*128*SEQ;
  int nt=qt+1;
  u16* pw=&Pl[wid][0];
  {
    #pragma unroll
    for(int i=0;i<4;i++){
      int fc=(wid*4+i)*64+lane;
      int row=fc>>4, g=(fc&15)^(row&15);
      gld16(kbase+(size_t)row*128+g*8, &Kl[0][(wid*4+i)*512]);
    }
    #pragma unroll
    for(int i=0;i<4;i++){
      int fc=(wid*4+i)*64+lane;
      int row=fc>>3, g=(fc&7)^(row&7);
      gld16(vtb+(size_t)row*2048+g*8, &Vl[0][(wid*4+i)*512]);
    }
  }
  __syncthreads();
  for(int tt=0;tt<nt;tt++){
    int cur=tt&1;
    if(tt+1<nt){
      int kv0n=(tt+1)*64, nb=cur^1;
      #pragma unroll
      for(int i=0;i<4;i++){
        int fc=(wid*4+i)*64+lane;
        int row=fc>>4, g=(fc&15)^(row&15);
        gld16(kbase+(size_t)(kv0n+row)*128+g*8, &Kl[nb][(wid*4+i)*512]);
      }
      #pragma unroll
      for(int i=0;i<4;i++){
        int fc=(wid*4+i)*64+lane;
        int row=fc>>3, g=(fc&7)^(row&7);
        gld16(vtb+(size_t)row*2048+kv0n+g*8, &Vl[nb][(wid*4+i)*512]);
      }
    }
    int kv0=tt*64;
    f32x4 s[4];
    #pragma unroll
    for(int ss=0;ss<4;ss++) s[ss]=f4zero();
    #pragma unroll
    for(int c=0;c<4;c++){
      #pragma unroll
      for(int ss=0;ss<4;ss++){
        int row=ss*16+fm;
        bf16x8 kf=*(const bf16x8*)&Kl[cur][row*128 + (((c*4+fo)^(row&15))*8)];
        s[ss]=mfma16(qfr[c],kf,s[ss]);
      }
    }
    bool diag=(tt==nt-1);
    int qg=qbase+wid*16+fo*4;
    #pragma unroll
    for(int r=0;r<4;r++){
      float v0=s[0][r]*ATT_SCALE, v1=s[1][r]*ATT_SCALE,
            v2=s[2][r]*ATT_SCALE, v3=s[3][r]*ATT_SCALE;
      if(diag){
        int qr=qg+r;
        if(kv0+   fm > qr) v0=-1e30f;
        if(kv0+16+fm > qr) v1=-1e30f;
        if(kv0+32+fm > qr) v2=-1e30f;
        if(kv0+48+fm > qr) v3=-1e30f;
      }
      float vm=fmaxf(fmaxf(v0,v1),fmaxf(v2,v3));
      vm=fmaxf(vm,__shfl_xor(vm,1)); vm=fmaxf(vm,__shfl_xor(vm,2));
      vm=fmaxf(vm,__shfl_xor(vm,4)); vm=fmaxf(vm,__shfl_xor(vm,8));
      float mn=fmaxf(mr[r],vm);
      float sc=__expf(mr[r]-mn);
      mr[r]=mn;
      float p0=__expf(v0-mn), p1=__expf(v1-mn),
            p2=__expf(v2-mn), p3=__expf(v3-mn);
      float rs=(p0+p1)+(p2+p3);
      rs+=__shfl_xor(rs,1); rs+=__shfl_xor(rs,2);
      rs+=__shfl_xor(rs,4); rs+=__shfl_xor(rs,8);
      ls[r]=ls[r]*sc+rs;
      #pragma unroll
      for(int dg=0;dg<8;dg++) o[dg][r]*=sc;
      int prow=(fo*4+r)*72;
      pw[prow+fm   ]=f2bf(p0);
      pw[prow+16+fm]=f2bf(p1);
      pw[prow+32+fm]=f2bf(p2);
      pw[prow+48+fm]=f2bf(p3);
    }
    #pragma unroll
    for(int kvs=0;kvs<2;kvs++){
      bf16x8 pa=*(const bf16x8*)&pw[fm*72 + kvs*32 + fo*8];
      #pragma unroll
      for(int dg=0;dg<8;dg++){
        int R=dg*16+fm;
        bf16x8 bv=*(const bf16x8*)&Vl[cur][R*64 + (((kvs*4+fo)^(R&7))*8)];
        o[dg]=mfma16(pa,bv,o[dg]);
      }
    }
    __syncthreads();
  }
  float sb=sink[h];
  float invd[4];
  #pragma unroll
  for(int r=0;r<4;r++) invd[r]=1.f/(ls[r]+__expf(sb-mr[r]));
  #pragma unroll
  for(int dg=0;dg<8;dg++)
    #pragma unroll
    for(int r=0;r<4;r++){
      int row=qbase+wid*16+fo*4+r;
      ao[(size_t)row*2048 + h*128 + dg*16 + fm]=f2bf(o[dg][r]*invd[r]);
    }
}

// ---------------- Fused RMSNorm + gate logits + routing ----------------
__global__ __launch_bounds__(256) void gate_route_k(const float* __restrict__ h1,
                                                    const float* __restrict__ lnw,
                                                    const float* __restrict__ gw,
                                                    const float* __restrict__ gb,
                                                    int* __restrict__ tsel,
                                                    float* __restrict__ twsel){
  int n=blockIdx.x, t=threadIdx.x, lane=t&63, wid=t>>6;
  const float* xr=h1+(size_t)n*2048;
  float4 a=*(const float4*)&xr[t*8], b=*(const float4*)&xr[t*8+4];
  float xv[8]={a.x,a.y,a.z,a.w,b.x,b.y,b.z,b.w};
  float ss=0.f;
  #pragma unroll
  for(int j=0;j<8;j++) ss+=xv[j]*xv[j];
  #pragma unroll
  for(int m=1;m<=32;m<<=1) ss+=__shfl_xor(ss,m);
  __shared__ float redn[4];
  if(lane==0) redn[wid]=ss;
  __syncthreads();
  float inv=rsqrtf((redn[0]+redn[1]+redn[2]+redn[3])*(1.0f/2048.0f)+1e-6f);
  const float* wr=lnw+t*8;
  float4 wa=*(const float4*)&wr[0], wb=*(const float4*)&wr[4];
  float wv[8]={wa.x,wa.y,wa.z,wa.w,wb.x,wb.y,wb.z,wb.w};
  #pragma unroll
  for(int j=0;j<8;j++) xv[j]*=inv*wv[j];
  float part[16];
  #pragma unroll
  for(int e=0;e<16;e++){
    const float* g=gw+(size_t)e*2048+t*8;
    float4 ga=*(const float4*)&g[0], gb2=*(const float4*)&g[4];
    part[e]=xv[0]*ga.x+xv[1]*ga.y+xv[2]*ga.z+xv[3]*ga.w
           +xv[4]*gb2.x+xv[5]*gb2.y+xv[6]*gb2.z+xv[7]*gb2.w;
  }
  #pragma unroll
  for(int e=0;e<16;e++)
    #pragma unroll
    for(int m=1;m<=32;m<<=1) part[e]+=__shfl_xor(part[e],m);
  __shared__ float red[4][16];
  __shared__ float lg[16];
  if(lane<16) red[wid][lane]=part[lane];
  __syncthreads();
  if(t<16) lg[t]=red[0][t]+red[1][t]+red[2][t]+red[3][t];
  __syncthreads();
  if(t==0){
    float sg[16], sfc[16];
    #pragma unroll
    for(int e=0;e<16;e++){ sg[e]=1.f/(1.f+__expf(-lg[e])); sfc[e]=sg[e]+gb[e]; }
    float gs[4];
    #pragma unroll
    for(int g=0;g<4;g++){
      const float* v=&sfc[g*4];
      int im=0;
      for(int j=1;j<4;j++) if(v[j]>v[im]) im=j;
      float m2=-1e30f;
      for(int j=0;j<4;j++) if(j!=im && v[j]>m2) m2=v[j];
      gs[g]=v[im]+m2;
    }
    int g1=0;
    for(int j=1;j<4;j++) if(gs[j]>gs[g1]) g1=j;
    int g2=-1;
    for(int j=0;j<4;j++){ if(j==g1) continue; if(g2<0||gs[j]>gs[g2]) g2=j; }
    bool used[16];
    for(int e=0;e<16;e++) used[e]=false;
    int ch[4]; float tw[4];
    for(int s=0;s<4;s++){
      int best=-1; float bvv=-1e30f;
      for(int e=0;e<16;e++){
        int g=e>>2;
        if(g!=g1 && g!=g2) continue;
        if(used[e]) continue;
        if(sfc[e]>bvv){ bvv=sfc[e]; best=e; }
      }
      used[best]=true; ch[s]=best; tw[s]=sg[best];
    }
    float ssum=tw[0]+tw[1]+tw[2]+tw[3]+1e-20f;
    float sc=2.5f/ssum;
    for(int s=0;s<4;s++){ tsel[n*4+s]=ch[s]; twsel[n*4+s]=tw[s]*sc; }
  }
}

// ---------------- histogram + scan + compact per-expert token lists ----------------
__global__ __launch_bounds__(256) void scan_fill_k(const int* __restrict__ tsel,
                                                   const float* __restrict__ twsel,
                                                   int* __restrict__ counts,
                                                   int* __restrict__ offsets,
                                                   int* __restrict__ toklist,
                                                   float* __restrict__ wslot,
                                                   int* __restrict__ slotof){
  __shared__ int cnt[16], off[16], cur[16];
  int t=threadIdx.x;
  if(t<16){ cnt[t]=0; cur[t]=0; }
  __syncthreads();
  for(int n=t;n<2048;n+=256)
    for(int j=0;j<4;j++) atomicAdd(&cnt[tsel[n*4+j]],1);
  __syncthreads();
  if(t==0){
    int run=0;
    for(int e=0;e<16;e++){ off[e]=run; run+=cnt[e]; }
  }
  __syncthreads();
  if(t<16){ counts[t]=cnt[t]; offsets[t]=off[t]; }
  for(int n=t;n<2048;n+=256)
    for(int j=0;j<4;j++){
      int e=tsel[n*4+j];
      int pos=atomicAdd(&cur[e],1);
      int slot=off[e]+pos;
      toklist[slot]=n;
      wslot[slot]=twsel[n*4+j];
      slotof[n*4+j]=slot;
    }
}

// ---------------- hgu = silu(g)*u*w ----------------
__global__ __launch_bounds__(256) void hgu_act_k(const u16* __restrict__ gu,
                                                 const float* __restrict__ wslot,
                                                 u16* __restrict__ hgu){
  int t=threadIdx.x;
  int slot=blockIdx.x*4+(t>>6);
  int f8=(t&63)*8;
  float wv=wslot[slot];
  uint4 gr=*(const uint4*)&gu[(size_t)slot*1024+f8];
  uint4 ur=*(const uint4*)&gu[(size_t)slot*1024+512+f8];
  const u16* gp=(const u16*)&gr;
  const u16* up=(const u16*)&ur;
  alignas(16) u16 o[8];
  #pragma unroll
  for(int j=0;j<8;j++){
    float g=bf2f(gp[j]), u=bf2f(up[j]);
    float s=g/(1.f+__expf(-g));
    o[j]=f2bf(s*u*wv);
  }
  *(uint4*)&hgu[(size_t)slot*512+f8]=*(uint4*)o;
}

extern "C" void kernel_launch(void* const* d_in, const int* in_sizes, int n_in,
                              void* d_out, int out_size, void* d_ws, size_t ws_size,
                              hipStream_t stream){
  const float* x    =(const float*)d_in[0];
  const float* cosb =(const float*)d_in[1];
  const float* sinb =(const float*)d_in[2];
  const float* ln1w =(const float*)d_in[3];
  const float* ln2w =(const float*)d_in[4];
  const float* Wq   =(const float*)d_in[5];
  const float* Wk   =(const float*)d_in[6];
  const float* Wv   =(const float*)d_in[7];
  const float* Wo   =(const float*)d_in[8];
  const float* sink =(const float*)d_in[9];
  const float* gw   =(const float*)d_in[10];
  const float* gb   =(const float*)d_in[11];
  const float* Weg  =(const float*)d_in[12];
  const float* Weu  =(const float*)d_in[13];
  const float* Wed  =(const float*)d_in[14];
  float* out=(float*)d_out;
  char* w=(char*)d_ws;
  const size_t MB=1024*1024;
  float* qkvf=(float*)(w+0);        // 24MB [2048][3072] ; later gu/hgu alias
  u16* gu =(u16*)(w+0);             // 16MB
  u16* hgu=(u16*)(w+16*MB);         // 8MB
  u16* xn =(u16*)(w+24*MB);         // 8MB
  u16* qb =(u16*)(w+32*MB);         // 8MB
  u16* kb =(u16*)(w+40*MB);         // 2MB
  u16* vbT=(u16*)(w+42*MB);         // 2MB [4][128][2048]
  u16* aob=(u16*)(w+44*MB);         // 8MB
  u16* xfb=(u16*)(w+52*MB);         // 8MB
  int*   tsel   =(int*)(w+60*MB);
  float* twsel  =(float*)(w+60*MB+32768);
  int*   counts =(int*)(w+60*MB+65536);
  int*   offsets=(int*)(w+60*MB+65536+256);
  int*   toklist=(int*)(w+60*MB+65536+512);
  float* wslot  =(float*)(w+60*MB+65536+512+32768);
  int*   slotof =(int*)(w+60*MB+65536+512+65536);
  char* wt=w+61*MB;
  u16* WqT=(u16*)(wt);              // 8MB  } contiguous ->
  u16* WkT=(u16*)(wt+8*MB);         // 2MB  }  one [3072][2048] B^T
  u16* WvT=(u16*)(wt+10*MB);        // 2MB  }
  u16* WoT=(u16*)(wt+12*MB);        // 8MB (ends 81MB)
  u16* WegT=(u16*)(wt);             // 32MB (after Wo gemm; dead after moe gemm1)
  u16* WeuT=(u16*)(wt+32*MB);       // 32MB (dead after moe gemm1; ends 125MB)
  u16* WedT=(u16*)(wt);             // 32MB (written after moe gemm1, over WegT)
  u16* moeb=(u16*)(wt+32*MB);       // 32MB slot-major moe output (over dead WeuT)

  dim3 blk(256);
  transpose_cvt_k<<<dim3(32,32,1),blk,0,stream>>>(Wq, WqT, 2048,2048, 0,0);
  transpose_cvt_k<<<dim3(8,32,1), blk,0,stream>>>(Wk, WkT, 2048,512, 0,0);
  transpose_cvt_k<<<dim3(8,32,1), blk,0,stream>>>(Wv, WvT, 2048,512, 0,0);
  transpose_cvt_k<<<dim3(32,32,1),blk,0,stream>>>(Wo, WoT, 2048,2048, 0,0);
  rmsnorm_k<<<dim3(2048),blk,0,stream>>>(x, ln1w, xn);
  gemm_bt_k<0><<<dim3(768),blk,0,stream>>>(xn, WqT,nullptr, qkvf,nullptr,nullptr,
                                           nullptr,nullptr,nullptr, 2048,3072, 32,24);
  rope_pack_k<<<dim3(2048),blk,0,stream>>>(qkvf,cosb,sinb,qb,kb);
  transpose_v_k<<<dim3(32,2,4),blk,0,stream>>>(qkvf, vbT);
  attn_k<<<dim3(16,32),blk,0,stream>>>(qb,kb,vbT,sink,aob);
  gemm_bt_k<1><<<dim3(512),blk,0,stream>>>(aob, WoT,nullptr, out,nullptr,x,
                                           nullptr,nullptr,nullptr, 2048,2048, 32,16);
  rmsnorm_k<<<dim3(2048),blk,0,stream>>>(out, ln2w, xfb);
  gate_route_k<<<dim3(2048),blk,0,stream>>>(out, ln2w, gw, gb, tsel, twsel);
  scan_fill_k<<<dim3(1),blk,0,stream>>>(tsel, twsel, counts, offsets, toklist, wslot, slotof);
  transpose_cvt_k<<<dim3(8,32,16),blk,0,stream>>>(Weg, WegT, 2048,512, 1048576,1048576);
  transpose_cvt_k<<<dim3(8,32,16),blk,0,stream>>>(Weu, WeuT, 2048,512, 1048576,1048576);
  gemm_bt_k<2><<<dim3(4096),blk,0,stream>>>(xfb, WegT,WeuT, nullptr,gu,nullptr,
                                            counts,offsets,toklist, 2048,1024, 32,8);
  hgu_act_k<<<dim3(2048),blk,0,stream>>>(gu, wslot, hgu);
  transpose_cvt_k<<<dim3(32,8,16),blk,0,stream>>>(Wed, WedT, 512,2048, 1048576,1048576);
  gemm_bt_k<3><<<dim3(8192),blk,0,stream>>>(hgu, WedT,nullptr, nullptr,moeb,nullptr,
                                            counts,offsets,toklist, 512,2048, 32,16);
  moe_reduce_k<<<dim3(2048),blk,0,stream>>>(moeb, slotof, out);
}

// Round 14
// 386.013 us; speedup vs baseline: 1.0367x; 1.0103x over previous
//
#include <hip/hip_runtime.h>
#include <math.h>

typedef unsigned short u16;
typedef __bf16 bf16x8 __attribute__((ext_vector_type(8)));
typedef float f32x4 __attribute__((ext_vector_type(4)));

#define SEQ 2048
#define ATT_SCALE 0.08838834764831845f

__device__ __forceinline__ u16 f2bf(float f){
  union{float f;unsigned u;}v; v.f=f;
  unsigned r=v.u + 0x7fffu + ((v.u>>16)&1u);
  return (u16)(r>>16);
}
__device__ __forceinline__ float bf2f(u16 u){
  union{unsigned u;float f;}v; v.u=((unsigned)u)<<16; return v.f;
}
__device__ __forceinline__ f32x4 f4zero(){ f32x4 v; v[0]=0.f;v[1]=0.f;v[2]=0.f;v[3]=0.f; return v; }
__device__ __forceinline__ f32x4 mfma16(bf16x8 a, bf16x8 b, f32x4 c){
  return __builtin_amdgcn_mfma_f32_16x16x32_bf16(a,b,c,0,0,0);
}

typedef const __attribute__((address_space(1))) unsigned char* gas1p;
typedef __attribute__((address_space(3))) unsigned char* las3p;
__device__ __forceinline__ void gld16(const void* g, void* l){
  __builtin_amdgcn_global_load_lds((gas1p)g, (las3p)l, 16, 0, 0);
}

// ---------------- transpose + fp32->bf16 convert: in[R,C] f32 -> out[C,R] bf16 ----------------
__global__ __launch_bounds__(256) void transpose_cvt_k(const float* __restrict__ in,
                                                       u16* __restrict__ out,
                                                       int R, int C,
                                                       size_t in_stride, size_t out_stride){
  const float* src = in + (size_t)blockIdx.z*in_stride;
  u16* dst = out + (size_t)blockIdx.z*out_stride;
  int tc = blockIdx.x*64;
  int tr = blockIdx.y*64;
  __shared__ float tile[64][65];
  int t=threadIdx.x;
  int lr=t>>4, lc=(t&15)*4;
  #pragma unroll
  for(int i=0;i<4;i++){
    float4 v=*(const float4*)&src[(size_t)(tr+lr+i*16)*C + tc+lc];
    tile[lr+i*16][lc+0]=v.x; tile[lr+i*16][lc+1]=v.y;
    tile[lr+i*16][lc+2]=v.z; tile[lr+i*16][lc+3]=v.w;
  }
  __syncthreads();
  int on=t>>2, kq=(t&3)*16;
  alignas(16) u16 ov[16];
  #pragma unroll
  for(int j=0;j<16;j++) ov[j]=f2bf(tile[kq+j][on]);
  *(uint4*)&dst[(size_t)(tc+on)*R + tr+kq]   = *(uint4*)&ov[0];
  *(uint4*)&dst[(size_t)(tc+on)*R + tr+kq+8] = *(uint4*)&ov[8];
}

// ---------------- V transpose (bf16 passthrough): qkvb[s][2560+kvh*128+d] -> vbT[kvh][d][s] ----------------
__global__ __launch_bounds__(256) void transpose_v_k(const u16* __restrict__ qkvb,
                                                     u16* __restrict__ vbT){
  int st=blockIdx.x*64, dt=blockIdx.y*64, kvh=blockIdx.z;
  __shared__ u16 tile[64][72];
  int t=threadIdx.x;
  #pragma unroll
  for(int i=0;i<2;i++){
    int f=i*256+t; int sr=f>>3, c8=(f&7)*8;
    uint4 v=*(const uint4*)&qkvb[(size_t)(st+sr)*3072 + 2560 + kvh*128 + dt + c8];
    *(uint4*)&tile[sr][c8]=v;
  }
  __syncthreads();
  #pragma unroll
  for(int i=0;i<2;i++){
    int f=i*256+t; int dr=f>>3, sc=(f&7)*8;
    alignas(16) u16 ov[8];
    #pragma unroll
    for(int j=0;j<8;j++) ov[j]=tile[sc+j][dr];
    *(uint4*)&vbT[((size_t)kvh*128 + dt+dr)*2048 + st + sc]=*(uint4*)ov;
  }
}

// ---------------- RMSNorm (fp32 in -> bf16 out) ----------------
__global__ __launch_bounds__(256) void rmsnorm_k(const float* __restrict__ x,
                                                 const float* __restrict__ w,
                                                 u16* __restrict__ o){
  int row=blockIdx.x, t=threadIdx.x;
  const float* xr = x + (size_t)row*2048;
  float4 a=*(const float4*)&xr[t*8], b=*(const float4*)&xr[t*8+4];
  float ss = a.x*a.x+a.y*a.y+a.z*a.z+a.w*a.w + b.x*b.x+b.y*b.y+b.z*b.z+b.w*b.w;
  #pragma unroll
  for(int m=1;m<=32;m<<=1) ss += __shfl_xor(ss,m);
  __shared__ float red[4];
  if((t&63)==0) red[t>>6]=ss;
  __syncthreads();
  float tot = red[0]+red[1]+red[2]+red[3];
  float inv = rsqrtf(tot*(1.0f/2048.0f)+1e-6f);
  const float* wr = w + t*8;
  float4 wa=*(const float4*)&wr[0], wb=*(const float4*)&wr[4];
  alignas(16) u16 ov[8];
  ov[0]=f2bf(a.x*inv*wa.x); ov[1]=f2bf(a.y*inv*wa.y);
  ov[2]=f2bf(a.z*inv*wa.z); ov[3]=f2bf(a.w*inv*wa.w);
  ov[4]=f2bf(b.x*inv*wb.x); ov[5]=f2bf(b.y*inv*wb.y);
  ov[6]=f2bf(b.z*inv*wb.z); ov[7]=f2bf(b.w*inv*wb.w);
  *(uint4*)&o[(size_t)row*2048 + t*8] = *(uint4*)ov;
}

// ---------------- Unified B^T GEMM: 64x128 tile, BK=64, dbuf, XCD-chunked swizzle ----------------
// MODE 0: Cf=acc fp32 ; MODE 1: Cf=hid+acc ; MODE 4: Cb=bf16(acc) dense (ldc arbitrary)
// MODE 2: MoE gemm1 (gather; bf16 out [slot,1024]) ; MODE 3: MoE gemm2 (slots; bf16 out [slot,2048])
template<int MODE>
__global__ __launch_bounds__(256) void gemm_bt_k(const u16* __restrict__ A,
                                                 const u16* __restrict__ BT0,
                                                 const u16* __restrict__ BT1,
                                                 float* __restrict__ Cf,
                                                 u16* __restrict__ Cb,
                                                 const float* __restrict__ hid,
                                                 const int* __restrict__ counts,
                                                 const int* __restrict__ offsets,
                                                 const int* __restrict__ toklist,
                                                 int K, int ldc, int NMT, int NBY){
  __shared__ alignas(16) u16 Al[2][64*64];
  __shared__ alignas(16) u16 Bl[2][128*64];
  __shared__ int slist[64];
  int t=threadIdx.x, lane=t&63, wid=t>>6;
  int nwg=gridDim.x, q=nwg>>3;
  int l=(blockIdx.x&7)*q + (blockIdx.x>>3);
  int e=0, mt, by;
  if constexpr(MODE==2||MODE==3){
    int per=NMT*NBY;
    e=l/per; int rem=l-e*per;
    mt=(rem%NMT)*64; by=rem/NMT;
  } else {
    mt=(l%NMT)*64; by=l/NMT;
  }
  int cnt=0, off=0;
  if constexpr(MODE==2||MODE==3){
    cnt=counts[e]; off=offsets[e];
    if(mt>=cnt) return;
  }
  const u16* Bbase;
  int cb=by*128;
  if constexpr(MODE==2){
    if(by<4) Bbase = BT0 + ((size_t)e*512 + by*128)*(size_t)K;
    else     Bbase = BT1 + ((size_t)e*512 + (by-4)*128)*(size_t)K;
  } else if constexpr(MODE==3){
    Bbase = BT0 + ((size_t)e*2048 + (size_t)cb)*(size_t)K;
  } else {
    Bbase = BT0 + (size_t)cb*(size_t)K;
  }
  if constexpr(MODE==2){
    if(t<64){
      int gr=mt+t; if(gr>=cnt) gr=cnt-1;
      slist[t]=toklist[off+gr];
    }
    __syncthreads();
  }
  int srow=t>>3;
  int sc=((t&7)^(srow&7))*8;
  const u16* aptr[2]; const u16* bptr[4];
  #pragma unroll
  for(int i=0;i<2;i++){
    int r=i*32+srow;
    size_t arow;
    if constexpr(MODE==2) arow=(size_t)slist[r];
    else if constexpr(MODE==3){ int s=off+mt+r; if(s>8191)s=8191; arow=(size_t)s; }
    else arow=(size_t)(mt+r);
    aptr[i]=A + arow*(size_t)K + sc;
  }
  #pragma unroll
  for(int i=0;i<4;i++){
    int r=i*32+srow;
    bptr[i]=Bbase + (size_t)r*(size_t)K + sc;
  }
  int fm=lane&15, fo=lane>>4;
  int wm=(wid>>1)*32, wn=(wid&1)*64;
  int aoff[2][2], boff[4][2];
  #pragma unroll
  for(int m=0;m<2;m++){
    int row=wm+m*16+fm;
    #pragma unroll
    for(int kk=0;kk<2;kk++) aoff[m][kk]=row*64 + (((kk*4+fo)^(row&7))*8);
  }
  #pragma unroll
  for(int n=0;n<4;n++){
    int row=wn+n*16+fm;
    #pragma unroll
    for(int kk=0;kk<2;kk++) boff[n][kk]=row*64 + (((kk*4+fo)^(row&7))*8);
  }
  f32x4 acc[2][4];
  #pragma unroll
  for(int m=0;m<2;m++)
    #pragma unroll
    for(int n=0;n<4;n++) acc[m][n]=f4zero();
  int ntk=K>>6;
  #pragma unroll
  for(int i=0;i<2;i++) gld16(aptr[i], &Al[0][i*2048+wid*512]);
  #pragma unroll
  for(int i=0;i<4;i++) gld16(bptr[i], &Bl[0][i*2048+wid*512]);
  __syncthreads();
  for(int kt=0;kt<ntk;kt++){
    int cur=kt&1;
    if(kt+1<ntk){
      int k0=(kt+1)<<6, nb=cur^1;
      #pragma unroll
      for(int i=0;i<2;i++) gld16(aptr[i]+k0, &Al[nb][i*2048+wid*512]);
      #pragma unroll
      for(int i=0;i<4;i++) gld16(bptr[i]+k0, &Bl[nb][i*2048+wid*512]);
    }
    bf16x8 af[2][2], bv[4][2];
    #pragma unroll
    for(int m=0;m<2;m++){
      af[m][0]=*(const bf16x8*)&Al[cur][aoff[m][0]];
      af[m][1]=*(const bf16x8*)&Al[cur][aoff[m][1]];
    }
    #pragma unroll
    for(int n=0;n<4;n++){
      bv[n][0]=*(const bf16x8*)&Bl[cur][boff[n][0]];
      bv[n][1]=*(const bf16x8*)&Bl[cur][boff[n][1]];
    }
    #pragma unroll
    for(int m=0;m<2;m++)
      #pragma unroll
      for(int n=0;n<4;n++){
        acc[m][n]=mfma16(af[m][0],bv[n][0],acc[m][n]);
        acc[m][n]=mfma16(af[m][1],bv[n][1],acc[m][n]);
      }
    __syncthreads();
  }
  #pragma unroll
  for(int m=0;m<2;m++)
    #pragma unroll
    for(int n=0;n<4;n++)
      #pragma unroll
      for(int r=0;r<4;r++){
        int lr=wm+m*16+fo*4+r;
        int col=cb+wn+n*16+fm;
        float v=acc[m][n][r];
        if constexpr(MODE==0){
          Cf[(size_t)(mt+lr)*ldc+col]=v;
        } else if constexpr(MODE==1){
          size_t idx=(size_t)(mt+lr)*ldc+col;
          Cf[idx]=v+hid[idx];
        } else if constexpr(MODE==4){
          Cb[(size_t)(mt+lr)*ldc+col]=f2bf(v);
        } else if constexpr(MODE==2){
          int gr=mt+lr;
          if(gr<cnt) Cb[(size_t)(off+gr)*1024+col]=f2bf(v);
        } else {
          int gr=mt+lr;
          if(gr<cnt) Cb[(size_t)(off+gr)*2048+col]=f2bf(v);
        }
      }
}

// ---------------- gather 4 slots per token and add into out ----------------
__global__ __launch_bounds__(256) void moe_reduce_k(const u16* __restrict__ moeb,
                                                    const int* __restrict__ slotof,
                                                    float* __restrict__ out){
  int n=blockIdx.x, t=threadIdx.x;
  int4 s4=*(const int4*)&slotof[n*4];
  int c=t*8;
  const u16* r0=moeb+(size_t)s4.x*2048+c;
  const u16* r1=moeb+(size_t)s4.y*2048+c;
  const u16* r2=moeb+(size_t)s4.z*2048+c;
  const u16* r3=moeb+(size_t)s4.w*2048+c;
  uint4 a=*(const uint4*)r0, b=*(const uint4*)r1,
        cc=*(const uint4*)r2, d=*(const uint4*)r3;
  const u16* pa=(const u16*)&a; const u16* pb=(const u16*)&b;
  const u16* pc=(const u16*)&cc; const u16* pd=(const u16*)&d;
  float* op=out+(size_t)n*2048+c;
  float4 o0=*(const float4*)op, o1=*(const float4*)(op+4);
  float ov[8]={o0.x,o0.y,o0.z,o0.w,o1.x,o1.y,o1.z,o1.w};
  #pragma unroll
  for(int j=0;j<8;j++)
    ov[j]+=bf2f(pa[j])+bf2f(pb[j])+bf2f(pc[j])+bf2f(pd[j]);
  *(float4*)op    =make_float4(ov[0],ov[1],ov[2],ov[3]);
  *(float4*)(op+4)=make_float4(ov[4],ov[5],ov[6],ov[7]);
}

// ---------------- RoPE + pack (reads bf16 qkvb, ld=3072) ----------------
__global__ __launch_bounds__(256) void rope_pack_k(const u16* __restrict__ qkvb,
                                                   const float* __restrict__ cosb,
                                                   const float* __restrict__ sinb,
                                                   u16* __restrict__ qb,
                                                   u16* __restrict__ kb){
  int s=blockIdx.x, t=threadIdx.x;
  __shared__ float cs[64], sn[64];
  if(t<64){ cs[t]=cosb[s*64+t]; sn[t]=sinb[s*64+t]; }
  __syncthreads();
  { // Q
    int idx=t*8; int d=idx&127;
    const u16* src=qkvb+(size_t)s*3072+idx;
    uint4 av=*(const uint4*)src;
    const u16* ap=(const u16*)&av;
    alignas(16) u16 o[8];
    if(d<64){
      const u16* ps=(d<32)? src+32 : src-32;
      uint4 pv=*(const uint4*)ps;
      const u16* pp=(const u16*)&pv;
      #pragma unroll
      for(int j=0;j<8;j++){
        float c=cs[d+j], si=sn[d+j];
        float vv=bf2f(ap[j]), pq=bf2f(pp[j]);
        float r=(d<32)? (vv*c - pq*si) : (vv*c + pq*si);
        o[j]=f2bf(r);
      }
    } else {
      #pragma unroll
      for(int j=0;j<8;j++) o[j]=ap[j];
    }
    *(uint4*)&qb[(size_t)s*2048+idx]=*(uint4*)o;
  }
  if(t<64){ // K
    int idx=t*8; int kvh=idx>>7; int d=idx&127;
    const u16* src=qkvb+(size_t)s*3072+2048+idx;
    uint4 av=*(const uint4*)src;
    const u16* ap=(const u16*)&av;
    alignas(16) u16 o[8];
    if(d<64){
      const u16* ps=(d<32)? src+32 : src-32;
      uint4 pv=*(const uint4*)ps;
      const u16* pp=(const u16*)&pv;
      #pragma unroll
      for(int j=0;j<8;j++){
        float c=cs[d+j], si=sn[d+j];
        float vv=bf2f(ap[j]), pq=bf2f(pp[j]);
        float r=(d<32)? (vv*c - pq*si) : (vv*c + pq*si);
        o[j]=f2bf(r);
      }
    } else {
      #pragma unroll
      for(int j=0;j<8;j++) o[j]=ap[j];
    }
    *(uint4*)&kb[((size_t)kvh*SEQ + s)*128 + d]=*(uint4*)o;
  }
}

// ---------------- Flash attention: QBLK=64, KVBLK=64, dbuf gld16 staging (r6 best-known) ----------------
__global__ __launch_bounds__(256) void attn_k(const u16* __restrict__ qb,
                                              const u16* __restrict__ kb,
                                              const u16* __restrict__ vbT,
                                              const float* __restrict__ sink,
                                              u16* __restrict__ ao){
  int h=blockIdx.x;
  int qt=31-blockIdx.y;
  int kvh=h>>2;
  int t=threadIdx.x, wid=t>>6, lane=t&63;
  int fm=lane&15, fo=lane>>4;
  int qbase=qt*64;
  __shared__ alignas(16) u16 Kl[2][64*128];
  __shared__ alignas(16) u16 Vl[2][128*64];
  __shared__ alignas(16) u16 Pl[4][16*72];
  bf16x8 qfr[4];
  int qrow=qbase+wid*16+fm;
  #pragma unroll
  for(int c=0;c<4;c++)
    qfr[c]=*(const bf16x8*)&qb[(size_t)qrow*2048 + h*128 + c*32 + fo*8];
  f32x4 o[8];
  #pragma unroll
  for(int dg=0;dg<8;dg++) o[dg]=f4zero();
  float mr[4]={-1e30f,-1e30f,-1e30f,-1e30f};
  float ls[4]={0.f,0.f,0.f,0.f};
  const u16* kbase=kb+(size_t)kvh*SEQ*128;
  const u16* vtb=vbT+(size_t)kvh*128*SEQ;
  int nt=qt+1;
  u16* pw=&Pl[wid][0];
  {
    #pragma unroll
    for(int i=0;i<4;i++){
      int fc=(wid*4+i)*64+lane;
      int row=fc>>4, g=(fc&15)^(row&15);
      gld16(kbase+(size_t)row*128+g*8, &Kl[0][(wid*4+i)*512]);
    }
    #pragma unroll
    for(int i=0;i<4;i++){
      int fc=(wid*4+i)*64+lane;
      int row=fc>>3, g=(fc&7)^(row&7);
      gld16(vtb+(size_t)row*2048+g*8, &Vl[0][(wid*4+i)*512]);
    }
  }
  __syncthreads();
  for(int tt=0;tt<nt;tt++){
    int cur=tt&1;
    if(tt+1<nt){
      int kv0n=(tt+1)*64, nb=cur^1;
      #pragma unroll
      for(int i=0;i<4;i++){
        int fc=(wid*4+i)*64+lane;
        int row=fc>>4, g=(fc&15)^(row&15);
        gld16(kbase+(size_t)(kv0n+row)*128+g*8, &Kl[nb][(wid*4+i)*512]);
      }
      #pragma unroll
      for(int i=0;i<4;i++){
        int fc=(wid*4+i)*64+lane;
        int row=fc>>3, g=(fc&7)^(row&7);
        gld16(vtb+(size_t)row*2048+kv0n+g*8, &Vl[nb][(wid*4+i)*512]);
      }
    }
    int kv0=tt*64;
    f32x4 s[4];
    #pragma unroll
    for(int ss=0;ss<4;ss++) s[ss]=f4zero();
    #pragma unroll
    for(int c=0;c<4;c++){
      #pragma unroll
      for(int ss=0;ss<4;ss++){
        int row=ss*16+fm;
        bf16x8 kf=*(const bf16x8*)&Kl[cur][row*128 + (((c*4+fo)^(row&15))*8)];
        s[ss]=mfma16(qfr[c],kf,s[ss]);
      }
    }
    bool diag=(tt==nt-1);
    int qg=qbase+wid*16+fo*4;
    #pragma unroll
    for(int r=0;r<4;r++){
      float v0=s[0][r]*ATT_SCALE, v1=s[1][r]*ATT_SCALE,
            v2=s[2][r]*ATT_SCALE, v3=s[3][r]*ATT_SCALE;
      if(diag){
        int qr=qg+r;
        if(kv0+   fm > qr) v0=-1e30f;
        if(kv0+16+fm > qr) v1=-1e30f;
        if(kv0+32+fm > qr) v2=-1e30f;
        if(kv0+48+fm > qr) v3=-1e30f;
      }
      float vm=fmaxf(fmaxf(v0,v1),fmaxf(v2,v3));
      vm=fmaxf(vm,__shfl_xor(vm,1)); vm=fmaxf(vm,__shfl_xor(vm,2));
      vm=fmaxf(vm,__shfl_xor(vm,4)); vm=fmaxf(vm,__shfl_xor(vm,8));
      float mn=fmaxf(mr[r],vm);
      float sc=__expf(mr[r]-mn);
      mr[r]=mn;
      float p0=__expf(v0-mn), p1=__expf(v1-mn),
            p2=__expf(v2-mn), p3=__expf(v3-mn);
      float rs=(p0+p1)+(p2+p3);
      rs+=__shfl_xor(rs,1); rs+=__shfl_xor(rs,2);
      rs+=__shfl_xor(rs,4); rs+=__shfl_xor(rs,8);
      ls[r]=ls[r]*sc+rs;
      #pragma unroll
      for(int dg=0;dg<8;dg++) o[dg][r]*=sc;
      int prow=(fo*4+r)*72;
      pw[prow+fm   ]=f2bf(p0);
      pw[prow+16+fm]=f2bf(p1);
      pw[prow+32+fm]=f2bf(p2);
      pw[prow+48+fm]=f2bf(p3);
    }
    #pragma unroll
    for(int kvs=0;kvs<2;kvs++){
      bf16x8 pa=*(const bf16x8*)&pw[fm*72 + kvs*32 + fo*8];
      #pragma unroll
      for(int dg=0;dg<8;dg++){
        int R=dg*16+fm;
        bf16x8 bv=*(const bf16x8*)&Vl[cur][R*64 + (((kvs*4+fo)^(R&7))*8)];
        o[dg]=mfma16(pa,bv,o[dg]);
      }
    }
    __syncthreads();
  }
  float sb=sink[h];
  float invd[4];
  #pragma unroll
  for(int r=0;r<4;r++) invd[r]=1.f/(ls[r]+__expf(sb-mr[r]));
  #pragma unroll
  for(int dg=0;dg<8;dg++)
    #pragma unroll
    for(int r=0;r<4;r++){
      int row=qbase+wid*16+fo*4+r;
      ao[(size_t)row*2048 + h*128 + dg*16 + fm]=f2bf(o[dg][r]*invd[r]);
    }
}

// ---------------- Fused ln2-RMSNorm + gate logits + routing + xfb store ----------------
__global__ __launch_bounds__(256) void gate_route_k(const float* __restrict__ h1,
                                                    const float* __restrict__ lnw,
                                                    const float* __restrict__ gw,
                                                    const float* __restrict__ gb,
                                                    int* __restrict__ tsel,
                                                    float* __restrict__ twsel,
                                                    u16* __restrict__ xfb){
  int n=blockIdx.x, t=threadIdx.x, lane=t&63, wid=t>>6;
  const float* xr=h1+(size_t)n*2048;
  float4 a=*(const float4*)&xr[t*8], b=*(const float4*)&xr[t*8+4];
  float xv[8]={a.x,a.y,a.z,a.w,b.x,b.y,b.z,b.w};
  float ss=0.f;
  #pragma unroll
  for(int j=0;j<8;j++) ss+=xv[j]*xv[j];
  #pragma unroll
  for(int m=1;m<=32;m<<=1) ss+=__shfl_xor(ss,m);
  __shared__ float redn[4];
  if(lane==0) redn[wid]=ss;
  __syncthreads();
  float inv=rsqrtf((redn[0]+redn[1]+redn[2]+redn[3])*(1.0f/2048.0f)+1e-6f);
  const float* wr=lnw+t*8;
  float4 wa=*(const float4*)&wr[0], wb=*(const float4*)&wr[4];
  float wv[8]={wa.x,wa.y,wa.z,wa.w,wb.x,wb.y,wb.z,wb.w};
  #pragma unroll
  for(int j=0;j<8;j++) xv[j]*=inv*wv[j];
  { // store normalized bf16 row (replaces the second rmsnorm kernel)
    alignas(16) u16 ovn[8];
    #pragma unroll
    for(int j=0;j<8;j++) ovn[j]=f2bf(xv[j]);
    *(uint4*)&xfb[(size_t)n*2048 + t*8]=*(uint4*)ovn;
  }
  float part[16];
  #pragma unroll
  for(int e=0;e<16;e++){
    const float* g=gw+(size_t)e*2048+t*8;
    float4 ga=*(const float4*)&g[0], gb2=*(const float4*)&g[4];
    part[e]=xv[0]*ga.x+xv[1]*ga.y+xv[2]*ga.z+xv[3]*ga.w
           +xv[4]*gb2.x+xv[5]*gb2.y+xv[6]*gb2.z+xv[7]*gb2.w;
  }
  #pragma unroll
  for(int e=0;e<16;e++)
    #pragma unroll
    for(int m=1;m<=32;m<<=1) part[e]+=__shfl_xor(part[e],m);
  __shared__ float red[4][16];
  __shared__ float lg[16];
  if(lane<16) red[wid][lane]=part[lane];
  __syncthreads();
  if(t<16) lg[t]=red[0][t]+red[1][t]+red[2][t]+red[3][t];
  __syncthreads();
  if(t==0){
    float sg[16], sfc[16];
    #pragma unroll
    for(int e=0;e<16;e++){ sg[e]=1.f/(1.f+__expf(-lg[e])); sfc[e]=sg[e]+gb[e]; }
    float gs[4];
    #pragma unroll
    for(int g=0;g<4;g++){
      const float* v=&sfc[g*4];
      int im=0;
      for(int j=1;j<4;j++) if(v[j]>v[im]) im=j;
      float m2=-1e30f;
      for(int j=0;j<4;j++) if(j!=im && v[j]>m2) m2=v[j];
      gs[g]=v[im]+m2;
    }
    int g1=0;
    for(int j=1;j<4;j++) if(gs[j]>gs[g1]) g1=j;
    int g2=-1;
    for(int j=0;j<4;j++){ if(j==g1) continue; if(g2<0||gs[j]>gs[g2]) g2=j; }
    bool used[16];
    for(int e=0;e<16;e++) used[e]=false;
    int ch[4]; float tw[4];
    for(int s=0;s<4;s++){
      int best=-1; float bvv=-1e30f;
      for(int e=0;e<16;e++){
        int g=e>>2;
        if(g!=g1 && g!=g2) continue;
        if(used[e]) continue;
        if(sfc[e]>bvv){ bvv=sfc[e]; best=e; }
      }
      used[best]=true; ch[s]=best; tw[s]=sg[best];
    }
    float ssum=tw[0]+tw[1]+tw[2]+tw[3]+1e-20f;
    float sc=2.5f/ssum;
    for(int s=0;s<4;s++){ tsel[n*4+s]=ch[s]; twsel[n*4+s]=tw[s]*sc; }
  }
}

// ---------------- histogram + scan + compact per-expert token lists ----------------
__global__ __launch_bounds__(256) void scan_fill_k(const int* __restrict__ tsel,
                                                   const float* __restrict__ twsel,
                                                   int* __restrict__ counts,
                                                   int* __restrict__ offsets,
                                                   int* __restrict__ toklist,
                                                   float* __restrict__ wslot,
                                                   int* __restrict__ slotof){
  __shared__ int cnt[16], off[16], cur[16];
  int t=threadIdx.x;
  if(t<16){ cnt[t]=0; cur[t]=0; }
  __syncthreads();
  for(int n=t;n<2048;n+=256)
    for(int j=0;j<4;j++) atomicAdd(&cnt[tsel[n*4+j]],1);
  __syncthreads();
  if(t==0){
    int run=0;
    for(int e=0;e<16;e++){ off[e]=run; run+=cnt[e]; }
  }
  __syncthreads();
  if(t<16){ counts[t]=cnt[t]; offsets[t]=off[t]; }
  for(int n=t;n<2048;n+=256)
    for(int j=0;j<4;j++){
      int e=tsel[n*4+j];
      int pos=atomicAdd(&cur[e],1);
      int slot=off[e]+pos;
      toklist[slot]=n;
      wslot[slot]=twsel[n*4+j];
      slotof[n*4+j]=slot;
    }
}

// ---------------- hgu = silu(g)*u*w ----------------
__global__ __launch_bounds__(256) void hgu_act_k(const u16* __restrict__ gu,
                                                 const float* __restrict__ wslot,
                                                 u16* __restrict__ hgu){
  int t=threadIdx.x;
  int slot=blockIdx.x*4+(t>>6);
  int f8=(t&63)*8;
  float wv=wslot[slot];
  uint4 gr=*(const uint4*)&gu[(size_t)slot*1024+f8];
  uint4 ur=*(const uint4*)&gu[(size_t)slot*1024+512+f8];
  const u16* gp=(const u16*)&gr;
  const u16* up=(const u16*)&ur;
  alignas(16) u16 o[8];
  #pragma unroll
  for(int j=0;j<8;j++){
    float g=bf2f(gp[j]), u=bf2f(up[j]);
    float s=g/(1.f+__expf(-g));
    o[j]=f2bf(s*u*wv);
  }
  *(uint4*)&hgu[(size_t)slot*512+f8]=*(uint4*)o;
}

extern "C" void kernel_launch(void* const* d_in, const int* in_sizes, int n_in,
                              void* d_out, int out_size, void* d_ws, size_t ws_size,
                              hipStream_t stream){
  const float* x    =(const float*)d_in[0];
  const float* cosb =(const float*)d_in[1];
  const float* sinb =(const float*)d_in[2];
  const float* ln1w =(const float*)d_in[3];
  const float* ln2w =(const float*)d_in[4];
  const float* Wq   =(const float*)d_in[5];
  const float* Wk   =(const float*)d_in[6];
  const float* Wv   =(const float*)d_in[7];
  const float* Wo   =(const float*)d_in[8];
  const float* sink =(const float*)d_in[9];
  const float* gw   =(const float*)d_in[10];
  const float* gb   =(const float*)d_in[11];
  const float* Weg  =(const float*)d_in[12];
  const float* Weu  =(const float*)d_in[13];
  const float* Wed  =(const float*)d_in[14];
  float* out=(float*)d_out;
  char* w=(char*)d_ws;
  const size_t MB=1024*1024;
  u16* qkvb=(u16*)(w+0);            // 12MB [2048][3072] bf16 ; later gu/hgu alias
  u16* gu =(u16*)(w+0);             // 16MB
  u16* hgu=(u16*)(w+16*MB);         // 8MB
  u16* xn =(u16*)(w+24*MB);         // 8MB
  u16* qb =(u16*)(w+32*MB);         // 8MB
  u16* kb =(u16*)(w+40*MB);         // 2MB
  u16* vbT=(u16*)(w+42*MB);         // 2MB [4][128][2048]
  u16* aob=(u16*)(w+44*MB);         // 8MB
  u16* xfb=(u16*)(w+52*MB);         // 8MB
  int*   tsel   =(int*)(w+60*MB);
  float* twsel  =(float*)(w+60*MB+32768);
  int*   counts =(int*)(w+60*MB+65536);
  int*   offsets=(int*)(w+60*MB+65536+256);
  int*   toklist=(int*)(w+60*MB+65536+512);
  float* wslot  =(float*)(w+60*MB+65536+512+32768);
  int*   slotof =(int*)(w+60*MB+65536+512+65536);
  char* wt=w+61*MB;
  u16* WqT=(u16*)(wt);              // 8MB  } contiguous ->
  u16* WkT=(u16*)(wt+8*MB);         // 2MB  }  one [3072][2048] B^T
  u16* WvT=(u16*)(wt+10*MB);        // 2MB  }
  u16* WoT=(u16*)(wt+12*MB);        // 8MB (ends 81MB)
  u16* WegT=(u16*)(wt);             // 32MB (after Wo gemm; dead after moe gemm1)
  u16* WeuT=(u16*)(wt+32*MB);       // 32MB (dead after moe gemm1; ends 125MB)
  u16* WedT=(u16*)(wt);             // 32MB (written after moe gemm1, over WegT)
  u16* moeb=(u16*)(wt+32*MB);       // 32MB slot-major moe output (over dead WeuT)

  dim3 blk(256);
  transpose_cvt_k<<<dim3(32,32,1),blk,0,stream>>>(Wq, WqT, 2048,2048, 0,0);
  transpose_cvt_k<<<dim3(8,32,1), blk,0,stream>>>(Wk, WkT, 2048,512, 0,0);
  transpose_cvt_k<<<dim3(8,32,1), blk,0,stream>>>(Wv, WvT, 2048,512, 0,0);
  transpose_cvt_k<<<dim3(32,32,1),blk,0,stream>>>(Wo, WoT, 2048,2048, 0,0);
  rmsnorm_k<<<dim3(2048),blk,0,stream>>>(x, ln1w, xn);
  gemm_bt_k<4><<<dim3(768),blk,0,stream>>>(xn, WqT,nullptr, nullptr,qkvb,nullptr,
                                           nullptr,nullptr,nullptr, 2048,3072, 32,24);
  rope_pack_k<<<dim3(2048),blk,0,stream>>>(qkvb,cosb,sinb,qb,kb);
  transpose_v_k<<<dim3(32,2,4),blk,0,stream>>>(qkvb, vbT);
  attn_k<<<dim3(16,32),blk,0,stream>>>(qb,kb,vbT,sink,aob);
  gemm_bt_k<1><<<dim3(512),blk,0,stream>>>(aob, WoT,nullptr, out,nullptr,x,
                                           nullptr,nullptr,nullptr, 2048,2048, 32,16);
  gate_route_k<<<dim3(2048),blk,0,stream>>>(out, ln2w, gw, gb, tsel, twsel, xfb);
  scan_fill_k<<<dim3(1),blk,0,stream>>>(tsel, twsel, counts, offsets, toklist, wslot, slotof);
  transpose_cvt_k<<<dim3(8,32,16),blk,0,stream>>>(Weg, WegT, 2048,512, 1048576,1048576);
  transpose_cvt_k<<<dim3(8,32,16),blk,0,stream>>>(Weu, WeuT, 2048,512, 1048576,1048576);
  gemm_bt_k<2><<<dim3(4096),blk,0,stream>>>(xfb, WegT,WeuT, nullptr,gu,nullptr,
                                            counts,offsets,toklist, 2048,1024, 32,8);
  hgu_act_k<<<dim3(2048),blk,0,stream>>>(gu, wslot, hgu);
  transpose_cvt_k<<<dim3(32,8,16),blk,0,stream>>>(Wed, WedT, 512,2048, 1048576,1048576);
  gemm_bt_k<3><<<dim3(8192),blk,0,stream>>>(hgu, WedT,nullptr, nullptr,moeb,nullptr,
                                            counts,offsets,toklist, 512,2048, 32,16);
  moe_reduce_k<<<dim3(2048),blk,0,stream>>>(moeb, slotof, out);
}